// Round 1
// baseline (151.283 us; speedup 1.0000x reference)
//
#include <hip/hip_runtime.h>
#include <hip/hip_bf16.h>
#include <math.h>

#define GS_N 4096
#define IMG_H 96
#define IMG_W 96
#define NPIX (IMG_H * IMG_W)
#define TILE_PX 16
#define TILES_X 6
#define NTILES (TILES_X * TILES_X)          // 36 tiles of 16x16 px
#define CHUNK 256

// SH constants
#define SH_C0 0.28209479177387814f
#define SH_C1 0.4886025119029199f
__device__ __constant__ float kC2[5] = {1.0925484305920792f, -1.0925484305920792f, 0.31539156525252005f, -1.0925484305920792f, 0.5462742152960396f};
__device__ __constant__ float kC3[7] = {-0.5900435899266435f, 2.890611442640554f, -0.4570457994644658f, 0.3731763325901154f, -0.4570457994644658f, 1.445305721320277f, -0.5900435899266435f};

// -------------------- Kernel 1: per-gaussian preprocessing --------------------
__global__ __launch_bounds__(256) void gs_prep(
    const float* __restrict__ pws, const float* __restrict__ low_shs,
    const float* __restrict__ high_shs, const float* __restrict__ alphas_raw,
    const float* __restrict__ scales_raw, const float* __restrict__ rots_raw,
    const float* __restrict__ Rcw, const float* __restrict__ tcw,
    const float* __restrict__ cam,
    float* __restrict__ areas_out,      // N*2, original order (part of d_out)
    float* __restrict__ depth_ws,       // N
    int*   __restrict__ rank_ws,        // N (zeroed here for the atomic partial-rank)
    float4* __restrict__ A_uns,         // {ux, uy, ci0, ci1}
    float4* __restrict__ B_uns,         // {ci2, alpha_eff, colR, colG}
    float* __restrict__ C_uns,          // colB
    float4* __restrict__ D_uns)         // {ux, uy, rx, ry} bbox (rx<0 => culled)
{
    int i = blockIdx.x * 256 + threadIdx.x;
    if (i >= GS_N) return;

    rank_ws[i] = 0;   // ws is poisoned 0xAA before every launch; zero it here

    float fx = cam[0], fy = cam[1], cxi = cam[2], cyi = cam[3];
    float R0 = Rcw[0], R1 = Rcw[1], R2 = Rcw[2];
    float R3 = Rcw[3], R4 = Rcw[4], R5 = Rcw[5];
    float R6 = Rcw[6], R7 = Rcw[7], R8 = Rcw[8];
    float t0 = tcw[0], t1 = tcw[1], t2 = tcw[2];

    float pwx = pws[3*i+0], pwy = pws[3*i+1], pwz = pws[3*i+2];

    // camera-space point: pcs = Rcw @ pw + tcw
    float pcx = R0*pwx + R1*pwy + R2*pwz + t0;
    float pcy = R3*pwx + R4*pwy + R5*pwz + t1;
    float pcz = R6*pwx + R7*pwy + R8*pwz + t2;

    float depth = pcz;
    float zs = (depth > 1e-6f) ? depth : 1e-6f;

    float ux = fx * pcx / zs + cxi;
    float uy = fy * pcy / zs + cyi;

    float alpha = 1.0f / (1.0f + expf(-alphas_raw[i]));

    float s0 = expf(scales_raw[3*i+0]);
    float s1 = expf(scales_raw[3*i+1]);
    float s2 = expf(scales_raw[3*i+2]);

    float qw = rots_raw[4*i+0], qx = rots_raw[4*i+1], qy = rots_raw[4*i+2], qz = rots_raw[4*i+3];
    float qn = sqrtf(qw*qw + qx*qx + qy*qy + qz*qz);
    qw /= qn; qx /= qn; qy /= qn; qz /= qn;

    float r00 = 1.0f - 2.0f*(qy*qy + qz*qz);
    float r01 = 2.0f*(qx*qy - qw*qz);
    float r02 = 2.0f*(qx*qz + qw*qy);
    float r10 = 2.0f*(qx*qy + qw*qz);
    float r11 = 1.0f - 2.0f*(qx*qx + qz*qz);
    float r12 = 2.0f*(qy*qz - qw*qx);
    float r20 = 2.0f*(qx*qz - qw*qy);
    float r21 = 2.0f*(qy*qz + qw*qx);
    float r22 = 1.0f - 2.0f*(qx*qx + qy*qy);

    // M = Rot * diag(scale)
    float m00 = r00*s0, m01 = r01*s1, m02 = r02*s2;
    float m10 = r10*s0, m11 = r11*s1, m12 = r12*s2;
    float m20 = r20*s0, m21 = r21*s1, m22 = r22*s2;

    // cov3d = M M^T (symmetric)
    float V00 = m00*m00 + m01*m01 + m02*m02;
    float V01 = m00*m10 + m01*m11 + m02*m12;
    float V02 = m00*m20 + m01*m21 + m02*m22;
    float V11 = m10*m10 + m11*m11 + m12*m12;
    float V12 = m10*m20 + m11*m21 + m12*m22;
    float V22 = m20*m20 + m21*m21 + m22*m22;

    float limx = 1.3f * ((float)IMG_W / (2.0f * fx));
    float limy = 1.3f * ((float)IMG_H / (2.0f * fy));
    float xzr = pcx / zs, yzr = pcy / zs;
    float txv = fminf(fmaxf(xzr, -limx), limx) * zs;
    float tyv = fminf(fmaxf(yzr, -limy), limy) * zs;

    float J00 = fx / zs, J02 = -fx * txv / (zs * zs);
    float J11 = fy / zs, J12 = -fy * tyv / (zs * zs);

    // T = J @ Rcw  (2x3)
    float T00 = J00*R0 + J02*R6, T01 = J00*R1 + J02*R7, T02 = J00*R2 + J02*R8;
    float T10 = J11*R3 + J12*R6, T11 = J11*R4 + J12*R7, T12 = J11*R5 + J12*R8;

    // TW = T @ cov3d
    float TW00 = T00*V00 + T01*V01 + T02*V02;
    float TW01 = T00*V01 + T01*V11 + T02*V12;
    float TW02 = T00*V02 + T01*V12 + T02*V22;
    float TW10 = T10*V00 + T11*V01 + T12*V02;
    float TW11 = T10*V01 + T11*V11 + T12*V12;
    float TW12 = T10*V02 + T11*V12 + T12*V22;

    // cov2d = TW @ T^T
    float c00 = TW00*T00 + TW01*T01 + TW02*T02;
    float c01 = TW00*T10 + TW01*T11 + TW02*T12;
    float c11 = TW10*T10 + TW11*T11 + TW12*T12;

    float a  = c00 + 0.3f;
    float b  = c01;
    float cc = c11 + 0.3f;
    float det = a * cc - b * b;
    float ci0 = cc / det;
    float ci1 = -b / det;
    float ci2 = a / det;

    float mid = 0.5f * (a + cc);
    float lam = mid + sqrtf(fmaxf(mid * mid - det, 0.1f));
    float radius = ceilf(3.0f * sqrtf(lam));
    areas_out[2*i + 0] = radius;
    areas_out[2*i + 1] = radius;

    // view dir: twc = -(Rcw^T @ tcw)
    float twcx = -(R0*t0 + R3*t1 + R6*t2);
    float twcy = -(R1*t0 + R4*t1 + R7*t2);
    float twcz = -(R2*t0 + R5*t1 + R8*t2);
    float dx = pwx - twcx, dy = pwy - twcy, dz = pwz - twcz;
    float dn = sqrtf(dx*dx + dy*dy + dz*dz);
    dx /= dn; dy /= dn; dz /= dn;

    float xx = dx*dx, yy = dy*dy, zz = dz*dz;
    float xy = dx*dy, yz = dy*dz, xz = dx*dz;

    // SH basis (16)
    float bas0  = SH_C0;
    float bas1  = -SH_C1 * dy;
    float bas2  =  SH_C1 * dz;
    float bas3  = -SH_C1 * dx;
    float bas4  = kC2[0] * xy;
    float bas5  = kC2[1] * yz;
    float bas6  = kC2[2] * (2.0f*zz - xx - yy);
    float bas7  = kC2[3] * xz;
    float bas8  = kC2[4] * (xx - yy);
    float bas9  = kC3[0] * dy * (3.0f*xx - yy);
    float bas10 = kC3[1] * xy * dz;
    float bas11 = kC3[2] * dy * (4.0f*zz - xx - yy);
    float bas12 = kC3[3] * dz * (2.0f*zz - 3.0f*xx - 3.0f*yy);
    float bas13 = kC3[4] * dx * (4.0f*zz - xx - yy);
    float bas14 = kC3[5] * dz * (xx - yy);
    float bas15 = kC3[6] * dx * (xx - 3.0f*yy);

    float col[3];
    #pragma unroll
    for (int c = 0; c < 3; ++c) {
        const float* hs = high_shs + 45*i + c;
        float acc = bas0 * low_shs[3*i + c];
        acc += bas1  * hs[0*3];
        acc += bas2  * hs[1*3];
        acc += bas3  * hs[2*3];
        acc += bas4  * hs[3*3];
        acc += bas5  * hs[4*3];
        acc += bas6  * hs[5*3];
        acc += bas7  * hs[6*3];
        acc += bas8  * hs[7*3];
        acc += bas9  * hs[8*3];
        acc += bas10 * hs[9*3];
        acc += bas11 * hs[10*3];
        acc += bas12 * hs[11*3];
        acc += bas13 * hs[12*3];
        acc += bas14 * hs[13*3];
        acc += bas15 * hs[14*3];
        col[c] = fmaxf(acc + 0.5f, 0.0f);
    }

    bool valid = depth > 0.2f;
    float al_eff = valid ? alpha : 0.0f;   // alpha=0 => ap=0 => same as reference masking

    // Visibility ellipse: ap>=1/255 <=> Q <= T, T = ln(255*alpha).
    // Max extent of {Q<=T} along x is sqrt(2*T*Cxx) (C = dilated covariance).
    // +1e-4 margin makes the cull strictly conservative vs float rounding.
    float Tthr = __logf(255.0f * al_eff) + 1e-4f;
    float rx = (Tthr > 0.0f) ? sqrtf(2.0f * Tthr * a)  : -1.0f;
    float ry = (Tthr > 0.0f) ? sqrtf(2.0f * Tthr * cc) : -1.0f;

    depth_ws[i] = depth;
    A_uns[i] = make_float4(ux, uy, ci0, ci1);
    B_uns[i] = make_float4(ci2, al_eff, col[0], col[1]);
    C_uns[i] = col[2];
    D_uns[i] = make_float4(ux, uy, rx, ry);
}

// -------------------- Kernel 2: tiled partial rank (16x16 tile grid) --------------------
// rank[i] = #{ j : depth[j] < depth[i]  or (depth[j]==depth[i] and j<i) }  (stable argsort)
__global__ __launch_bounds__(256) void gs_rank_partial(
    const float* __restrict__ depth, int* __restrict__ rank_ws)
{
    __shared__ float sd[256];
    int itile = blockIdx.x >> 4;
    int jtile = blockIdx.x & 15;
    int tid = threadIdx.x;
    int i = itile * 256 + tid;

    sd[tid] = depth[jtile * 256 + tid];
    __syncthreads();

    float mg = depth[i];
    int jbase = jtile * 256;
    int rank = 0;
    const float4* s4 = (const float4*)sd;   // broadcast reads: all lanes same addr
    #pragma unroll 16
    for (int jj = 0; jj < 64; ++jj) {
        float4 v = s4[jj];
        int j0 = jbase + jj * 4;
        rank += (v.x < mg || (v.x == mg && (j0+0) < i)) ? 1 : 0;
        rank += (v.y < mg || (v.y == mg && (j0+1) < i)) ? 1 : 0;
        rank += (v.z < mg || (v.z == mg && (j0+2) < i)) ? 1 : 0;
        rank += (v.w < mg || (v.w == mg && (j0+3) < i)) ? 1 : 0;
    }
    atomicAdd(&rank_ws[i], rank);
}

// -------------------- Kernel 3: fused invert + bin + raster, one block per tile ------
// Block = 256 threads = 256 pixels of a 16x16 tile.
//  A) invert rank permutation into LDS (replaces gs_gather; sorted SoA copies gone)
//  B) walk gaussians in depth order, ballot-compact survivors of this tile's bbox
//     test into an LDS list (replaces gs_bin; order-preserving, race-free register base)
//  C) thread-per-pixel sequential alpha compositing over LDS-staged chunks
//     (replaces gs_raster; no prefix-product shuffle chains; exact early exit since
//      tau is monotone nonincreasing and reference zeroes weights once tau<=1e-4)
__global__ __launch_bounds__(256) void gs_tile(
    const int* __restrict__ rank_ws,
    const float4* __restrict__ A_uns, const float4* __restrict__ B_uns,
    const float* __restrict__ C_uns, const float4* __restrict__ D_uns,
    float* __restrict__ img)
{
    __shared__ int order_lds[GS_N];      // 16 KB
    __shared__ int list[GS_N];           // 16 KB (worst case: all gaussians hit one tile)
    __shared__ float4 sA[CHUNK];         // 4 KB
    __shared__ float4 sB[CHUNK];         // 4 KB
    __shared__ float  sC[CHUNK];         // 1 KB
    __shared__ int warp_off[4];

    int tid = threadIdx.x;
    int tile = blockIdx.x;
    int tx = tile % TILES_X, ty = tile / TILES_X;

    // ---- Phase A: order[rank[i]] = i ----
    #pragma unroll
    for (int i = tid; i < GS_N; i += 256) order_lds[rank_ws[i]] = i;
    __syncthreads();

    // ---- Phase B: bin this tile (depth-ordered compaction into LDS) ----
    float x0 = (float)(tx * TILE_PX), x1 = (float)(tx * TILE_PX + TILE_PX - 1);
    float y0 = (float)(ty * TILE_PX), y1 = (float)(ty * TILE_PX + TILE_PX - 1);
    int lane = tid & 63, w = tid >> 6;
    int base = 0;                        // running list length, uniform across block
    for (int r0 = 0; r0 < GS_N; r0 += 256) {
        int i = order_lds[r0 + tid];
        float4 d = D_uns[i];
        bool pred = (d.z >= 0.0f) &&
                    (d.x - d.z <= x1) && (d.x + d.z >= x0) &&
                    (d.y - d.w <= y1) && (d.y + d.w >= y0);
        unsigned long long m = __ballot(pred);
        int before = __popcll(m & ((1ull << lane) - 1ull));
        int wcnt = __popcll(m);
        if (lane == 0) warp_off[w] = wcnt;
        __syncthreads();
        int o0 = warp_off[0], o1 = warp_off[1], o2 = warp_off[2], o3 = warp_off[3];
        int off = base + ((w > 0) ? o0 : 0) + ((w > 1) ? o1 : 0) + ((w > 2) ? o2 : 0);
        if (pred) list[off + before] = i;
        base += o0 + o1 + o2 + o3;       // register copy, identical in every thread
        __syncthreads();                 // list writes done; warp_off safe to overwrite
    }
    int cnt = base;

    // ---- Phase C: thread-per-pixel compositing ----
    int lx = tid & (TILE_PX - 1), ly = tid >> 4;
    int pxi = tx * TILE_PX + lx, pyi = ty * TILE_PX + ly;
    float px = (float)pxi, py = (float)pyi;
    int p = pyi * IMG_W + pxi;

    float tau = 1.0f;
    float accr = 0.0f, accg = 0.0f, accb = 0.0f;
    bool done = false;

    for (int c0 = 0; c0 < cnt; c0 += CHUNK) {
        int k = c0 + tid;
        if (k < cnt) {
            int n = list[k];
            sA[tid] = A_uns[n];
            sB[tid] = B_uns[n];
            sC[tid] = C_uns[n];
        }
        __syncthreads();
        int mm = min(CHUNK, cnt - c0);
        if (!done) {
            for (int j = 0; j < mm; ++j) {
                float4 a4 = sA[j];          // same addr across lanes: LDS broadcast
                float4 b4 = sB[j];
                float ddx = a4.x - px;
                float ddy = a4.y - py;
                float pw = -0.5f * (a4.z * ddx * ddx + b4.x * ddy * ddy) - a4.w * ddx * ddy;
                pw = fminf(pw, 0.0f);
                float ap = b4.y * __expf(pw);
                ap = fminf(ap, 0.99f);
                ap = (ap >= (1.0f / 255.0f)) ? ap : 0.0f;
                float wgt = ap * tau;       // tau > 1e-4 guaranteed here (break below)
                accr += b4.z * wgt;
                accg += b4.w * wgt;
                accb += sC[j] * wgt;
                tau *= 1.0f - ap;
                if (tau <= 1e-4f) { done = true; break; }
            }
        }
        if (__syncthreads_and((int)done)) break;   // barrier + block-wide early exit
    }

    img[0 * NPIX + p] = accr;
    img[1 * NPIX + p] = accg;
    img[2 * NPIX + p] = accb;
}

extern "C" void kernel_launch(void* const* d_in, const int* in_sizes, int n_in,
                              void* d_out, int out_size, void* d_ws, size_t ws_size,
                              hipStream_t stream) {
    const float* pws        = (const float*)d_in[0];
    const float* low_shs    = (const float*)d_in[1];
    const float* high_shs   = (const float*)d_in[2];
    const float* alphas_raw = (const float*)d_in[3];
    const float* scales_raw = (const float*)d_in[4];
    const float* rots_raw   = (const float*)d_in[5];
    // d_in[6] = us (unused by the forward pass)
    const float* Rcw        = (const float*)d_in[7];
    const float* tcw        = (const float*)d_in[8];
    const float* cam        = (const float*)d_in[9];

    float* out_img   = (float*)d_out;             // 3*96*96
    float* out_areas = (float*)d_out + 3 * NPIX;  // N*2

    // workspace layout (bytes); ws_size is 256 MB — we use ~240 KB
    char* ws = (char*)d_ws;
    float*  depth_ws = (float*) (ws + 0);          // 16 KB
    int*    rank_ws  = (int*)   (ws + 16384);      // 16 KB
    float4* A_uns    = (float4*)(ws + 32768);      // 64 KB
    float4* B_uns    = (float4*)(ws + 98304);      // 64 KB
    float*  C_uns    = (float*) (ws + 163840);     // 16 KB
    float4* D_uns    = (float4*)(ws + 180224);     // 64 KB

    gs_prep<<<GS_N / 256, 256, 0, stream>>>(
        pws, low_shs, high_shs, alphas_raw, scales_raw, rots_raw, Rcw, tcw, cam,
        out_areas, depth_ws, rank_ws, A_uns, B_uns, C_uns, D_uns);

    gs_rank_partial<<<256, 256, 0, stream>>>(depth_ws, rank_ws);

    gs_tile<<<NTILES, 256, 0, stream>>>(
        rank_ws, A_uns, B_uns, C_uns, D_uns, out_img);
}

// Round 2
// 101.758 us; speedup vs baseline: 1.4867x; 1.4867x over previous
//
#include <hip/hip_runtime.h>
#include <hip/hip_bf16.h>
#include <math.h>

#define GS_N 4096
#define IMG_H 96
#define IMG_W 96
#define NPIX (IMG_H * IMG_W)
#define TILE_PX 12
#define TILES_X 8
#define NTILES (TILES_X * TILES_X)          // 64 tiles of 12x12 px
#define WAVES_PER_TILE 36                    // 144 px / 4 waves-per-block

// SH constants
#define SH_C0 0.28209479177387814f
#define SH_C1 0.4886025119029199f
__device__ __constant__ float kC2[5] = {1.0925484305920792f, -1.0925484305920792f, 0.31539156525252005f, -1.0925484305920792f, 0.5462742152960396f};
__device__ __constant__ float kC3[7] = {-0.5900435899266435f, 2.890611442640554f, -0.4570457994644658f, 0.3731763325901154f, -0.4570457994644658f, 1.445305721320277f, -0.5900435899266435f};

// -------------------- Kernel 1: per-gaussian preprocessing --------------------
__global__ __launch_bounds__(256) void gs_prep(
    const float* __restrict__ pws, const float* __restrict__ low_shs,
    const float* __restrict__ high_shs, const float* __restrict__ alphas_raw,
    const float* __restrict__ scales_raw, const float* __restrict__ rots_raw,
    const float* __restrict__ Rcw, const float* __restrict__ tcw,
    const float* __restrict__ cam,
    float* __restrict__ areas_out,      // N*2, original order (part of d_out)
    float* __restrict__ depth_ws,       // N
    int*   __restrict__ rank_ws,        // N (zeroed here for the atomic partial-rank)
    float4* __restrict__ A_uns,         // {ux, uy, ci0, ci1}
    float4* __restrict__ B_uns,         // {ci2, alpha_eff, colR, colG}
    float* __restrict__ C_uns,          // colB
    float4* __restrict__ D_uns)         // {ux, uy, rx, ry} bbox (rx<0 => culled)
{
    int i = blockIdx.x * 256 + threadIdx.x;
    if (i >= GS_N) return;

    rank_ws[i] = 0;   // ws is poisoned 0xAA before every launch; zero it here

    float fx = cam[0], fy = cam[1], cxi = cam[2], cyi = cam[3];
    float R0 = Rcw[0], R1 = Rcw[1], R2 = Rcw[2];
    float R3 = Rcw[3], R4 = Rcw[4], R5 = Rcw[5];
    float R6 = Rcw[6], R7 = Rcw[7], R8 = Rcw[8];
    float t0 = tcw[0], t1 = tcw[1], t2 = tcw[2];

    float pwx = pws[3*i+0], pwy = pws[3*i+1], pwz = pws[3*i+2];

    // camera-space point: pcs = Rcw @ pw + tcw
    float pcx = R0*pwx + R1*pwy + R2*pwz + t0;
    float pcy = R3*pwx + R4*pwy + R5*pwz + t1;
    float pcz = R6*pwx + R7*pwy + R8*pwz + t2;

    float depth = pcz;
    float zs = (depth > 1e-6f) ? depth : 1e-6f;

    float ux = fx * pcx / zs + cxi;
    float uy = fy * pcy / zs + cyi;

    float alpha = 1.0f / (1.0f + expf(-alphas_raw[i]));

    float s0 = expf(scales_raw[3*i+0]);
    float s1 = expf(scales_raw[3*i+1]);
    float s2 = expf(scales_raw[3*i+2]);

    float qw = rots_raw[4*i+0], qx = rots_raw[4*i+1], qy = rots_raw[4*i+2], qz = rots_raw[4*i+3];
    float qn = sqrtf(qw*qw + qx*qx + qy*qy + qz*qz);
    qw /= qn; qx /= qn; qy /= qn; qz /= qn;

    float r00 = 1.0f - 2.0f*(qy*qy + qz*qz);
    float r01 = 2.0f*(qx*qy - qw*qz);
    float r02 = 2.0f*(qx*qz + qw*qy);
    float r10 = 2.0f*(qx*qy + qw*qz);
    float r11 = 1.0f - 2.0f*(qx*qx + qz*qz);
    float r12 = 2.0f*(qy*qz - qw*qx);
    float r20 = 2.0f*(qx*qz - qw*qy);
    float r21 = 2.0f*(qy*qz + qw*qx);
    float r22 = 1.0f - 2.0f*(qx*qx + qy*qy);

    // M = Rot * diag(scale)
    float m00 = r00*s0, m01 = r01*s1, m02 = r02*s2;
    float m10 = r10*s0, m11 = r11*s1, m12 = r12*s2;
    float m20 = r20*s0, m21 = r21*s1, m22 = r22*s2;

    // cov3d = M M^T (symmetric)
    float V00 = m00*m00 + m01*m01 + m02*m02;
    float V01 = m00*m10 + m01*m11 + m02*m12;
    float V02 = m00*m20 + m01*m21 + m02*m22;
    float V11 = m10*m10 + m11*m11 + m12*m12;
    float V12 = m10*m20 + m11*m21 + m12*m22;
    float V22 = m20*m20 + m21*m21 + m22*m22;

    float limx = 1.3f * ((float)IMG_W / (2.0f * fx));
    float limy = 1.3f * ((float)IMG_H / (2.0f * fy));
    float xzr = pcx / zs, yzr = pcy / zs;
    float txv = fminf(fmaxf(xzr, -limx), limx) * zs;
    float tyv = fminf(fmaxf(yzr, -limy), limy) * zs;

    float J00 = fx / zs, J02 = -fx * txv / (zs * zs);
    float J11 = fy / zs, J12 = -fy * tyv / (zs * zs);

    // T = J @ Rcw  (2x3)
    float T00 = J00*R0 + J02*R6, T01 = J00*R1 + J02*R7, T02 = J00*R2 + J02*R8;
    float T10 = J11*R3 + J12*R6, T11 = J11*R4 + J12*R7, T12 = J11*R5 + J12*R8;

    // TW = T @ cov3d
    float TW00 = T00*V00 + T01*V01 + T02*V02;
    float TW01 = T00*V01 + T01*V11 + T02*V12;
    float TW02 = T00*V02 + T01*V12 + T02*V22;
    float TW10 = T10*V00 + T11*V01 + T12*V02;
    float TW11 = T10*V01 + T11*V11 + T12*V12;
    float TW12 = T10*V02 + T11*V12 + T12*V22;

    // cov2d = TW @ T^T
    float c00 = TW00*T00 + TW01*T01 + TW02*T02;
    float c01 = TW00*T10 + TW01*T11 + TW02*T12;
    float c11 = TW10*T10 + TW11*T11 + TW12*T12;

    float a  = c00 + 0.3f;
    float b  = c01;
    float cc = c11 + 0.3f;
    float det = a * cc - b * b;
    float ci0 = cc / det;
    float ci1 = -b / det;
    float ci2 = a / det;

    float mid = 0.5f * (a + cc);
    float lam = mid + sqrtf(fmaxf(mid * mid - det, 0.1f));
    float radius = ceilf(3.0f * sqrtf(lam));
    areas_out[2*i + 0] = radius;
    areas_out[2*i + 1] = radius;

    // view dir: twc = -(Rcw^T @ tcw)
    float twcx = -(R0*t0 + R3*t1 + R6*t2);
    float twcy = -(R1*t0 + R4*t1 + R7*t2);
    float twcz = -(R2*t0 + R5*t1 + R8*t2);
    float dx = pwx - twcx, dy = pwy - twcy, dz = pwz - twcz;
    float dn = sqrtf(dx*dx + dy*dy + dz*dz);
    dx /= dn; dy /= dn; dz /= dn;

    float xx = dx*dx, yy = dy*dy, zz = dz*dz;
    float xy = dx*dy, yz = dy*dz, xz = dx*dz;

    // SH basis (16)
    float bas0  = SH_C0;
    float bas1  = -SH_C1 * dy;
    float bas2  =  SH_C1 * dz;
    float bas3  = -SH_C1 * dx;
    float bas4  = kC2[0] * xy;
    float bas5  = kC2[1] * yz;
    float bas6  = kC2[2] * (2.0f*zz - xx - yy);
    float bas7  = kC2[3] * xz;
    float bas8  = kC2[4] * (xx - yy);
    float bas9  = kC3[0] * dy * (3.0f*xx - yy);
    float bas10 = kC3[1] * xy * dz;
    float bas11 = kC3[2] * dy * (4.0f*zz - xx - yy);
    float bas12 = kC3[3] * dz * (2.0f*zz - 3.0f*xx - 3.0f*yy);
    float bas13 = kC3[4] * dx * (4.0f*zz - xx - yy);
    float bas14 = kC3[5] * dz * (xx - yy);
    float bas15 = kC3[6] * dx * (xx - 3.0f*yy);

    float col[3];
    #pragma unroll
    for (int c = 0; c < 3; ++c) {
        const float* hs = high_shs + 45*i + c;
        float acc = bas0 * low_shs[3*i + c];
        acc += bas1  * hs[0*3];
        acc += bas2  * hs[1*3];
        acc += bas3  * hs[2*3];
        acc += bas4  * hs[3*3];
        acc += bas5  * hs[4*3];
        acc += bas6  * hs[5*3];
        acc += bas7  * hs[6*3];
        acc += bas8  * hs[7*3];
        acc += bas9  * hs[8*3];
        acc += bas10 * hs[9*3];
        acc += bas11 * hs[10*3];
        acc += bas12 * hs[11*3];
        acc += bas13 * hs[12*3];
        acc += bas14 * hs[13*3];
        acc += bas15 * hs[14*3];
        col[c] = fmaxf(acc + 0.5f, 0.0f);
    }

    bool valid = depth > 0.2f;
    float al_eff = valid ? alpha : 0.0f;   // alpha=0 => ap=0 => same as reference masking

    // Visibility ellipse: ap>=1/255 <=> Q <= T, T = ln(255*alpha).
    // Max extent of {Q<=T} along x is sqrt(2*T*Cxx) (C = dilated covariance).
    // +1e-4 margin makes the cull strictly conservative vs float rounding.
    float Tthr = __logf(255.0f * al_eff) + 1e-4f;
    float rx = (Tthr > 0.0f) ? sqrtf(2.0f * Tthr * a)  : -1.0f;
    float ry = (Tthr > 0.0f) ? sqrtf(2.0f * Tthr * cc) : -1.0f;

    depth_ws[i] = depth;
    A_uns[i] = make_float4(ux, uy, ci0, ci1);
    B_uns[i] = make_float4(ci2, al_eff, col[0], col[1]);
    C_uns[i] = col[2];
    D_uns[i] = make_float4(ux, uy, rx, ry);
}

// -------------------- Kernel 2: tiled partial rank (16x16 tile grid) --------------------
// rank[i] = #{ j : depth[j] < depth[i]  or (depth[j]==depth[i] and j<i) }  (stable argsort)
__global__ __launch_bounds__(256) void gs_rank_partial(
    const float* __restrict__ depth, int* __restrict__ rank_ws)
{
    __shared__ float sd[256];
    int itile = blockIdx.x >> 4;
    int jtile = blockIdx.x & 15;
    int tid = threadIdx.x;
    int i = itile * 256 + tid;

    sd[tid] = depth[jtile * 256 + tid];
    __syncthreads();

    float mg = depth[i];
    int jbase = jtile * 256;
    int rank = 0;
    const float4* s4 = (const float4*)sd;   // broadcast reads: all lanes same addr
    #pragma unroll 16
    for (int jj = 0; jj < 64; ++jj) {
        float4 v = s4[jj];
        int j0 = jbase + jj * 4;
        rank += (v.x < mg || (v.x == mg && (j0+0) < i)) ? 1 : 0;
        rank += (v.y < mg || (v.y == mg && (j0+1) < i)) ? 1 : 0;
        rank += (v.z < mg || (v.z == mg && (j0+2) < i)) ? 1 : 0;
        rank += (v.w < mg || (v.w == mg && (j0+3) < i)) ? 1 : 0;
    }
    atomicAdd(&rank_ws[i], rank);
}

// -------------------- Kernel 3: order-inversion + per-tile binning --------------------
// One block per 12x12 tile. Builds order[rank]=i in LDS (replaces gs_gather), then
// walks gaussians in depth order, ballot-compacting ORIGINAL indices of those whose
// conservative bbox intersects the tile into tile_list (depth order preserved).
__global__ __launch_bounds__(256) void gs_bin2(
    const int* __restrict__ rank_ws,
    const float4* __restrict__ D_uns,
    int* __restrict__ tile_list, int* __restrict__ tile_cnt)
{
    __shared__ int order_lds[GS_N];     // 16 KB
    __shared__ int warp_off[4];
    int tile = blockIdx.x;
    int tx = tile & (TILES_X - 1), ty = tile >> 3;
    float x0 = (float)(tx * TILE_PX), x1 = (float)(tx * TILE_PX + TILE_PX - 1);
    float y0 = (float)(ty * TILE_PX), y1 = (float)(ty * TILE_PX + TILE_PX - 1);

    int tid = threadIdx.x;
    int lane = tid & 63, w = tid >> 6;

    // invert the rank permutation: order[rank[i]] = i
    #pragma unroll
    for (int i = tid; i < GS_N; i += 256) order_lds[rank_ws[i]] = i;
    __syncthreads();

    int* list = tile_list + tile * GS_N;
    int base = 0;                        // running list length, uniform across block

    for (int r0 = 0; r0 < GS_N; r0 += 256) {
        int i = order_lds[r0 + tid];     // original index, depth order
        float4 d = D_uns[i];
        bool pred = (d.z >= 0.0f) &&
                    (d.x - d.z <= x1) && (d.x + d.z >= x0) &&
                    (d.y - d.w <= y1) && (d.y + d.w >= y0);
        unsigned long long m = __ballot(pred);
        int before = __popcll(m & ((1ull << lane) - 1ull));
        int wcnt = __popcll(m);
        if (lane == 0) warp_off[w] = wcnt;
        __syncthreads();
        int o0 = warp_off[0], o1 = warp_off[1], o2 = warp_off[2], o3 = warp_off[3];
        int off = base + ((w > 0) ? o0 : 0) + ((w > 1) ? o1 : 0) + ((w > 2) ? o2 : 0);
        if (pred) list[off + before] = i;
        base += o0 + o1 + o2 + o3;       // register copy, identical in every thread
        __syncthreads();                 // list writes done; warp_off safe to overwrite
    }
    if (tid == 0) tile_cnt[tile] = base;
}

// -------------------- Kernel 4: wave-per-pixel compositing over tile list -----------
// Block = 4 waves = 4 pixels of one tile; 36 blocks per tile. Lane l evaluates
// list entry chunk*64+l; shfl_up prefix product of (1-ap) gives exact per-entry
// transmittance. Entries outside the list contribute f=1 (identity).
__global__ __launch_bounds__(256) void gs_raster(
    const float4* __restrict__ A_uns, const float4* __restrict__ B_uns,
    const float* __restrict__ C_uns,
    const int* __restrict__ tile_list, const int* __restrict__ tile_cnt,
    float* __restrict__ img)
{
    int b = blockIdx.x;                    // 64 * 36 = 2304 blocks
    int tile = b / WAVES_PER_TILE;
    int sub  = b - tile * WAVES_PER_TILE;
    int lane = threadIdx.x & 63;
    int wv   = threadIdx.x >> 6;

    int idxp = sub * 4 + wv;               // 0..143 within tile
    int lx = idxp % TILE_PX, ly = idxp / TILE_PX;
    int tx = tile & (TILES_X - 1), ty = tile >> 3;
    int pxi = tx * TILE_PX + lx, pyi = ty * TILE_PX + ly;
    float px = (float)pxi, py = (float)pyi;
    int p = pyi * IMG_W + pxi;

    int cnt = tile_cnt[tile];
    const int* list = tile_list + tile * GS_N;

    float carry = 1.0f;
    float accr = 0.0f, accg = 0.0f, accb = 0.0f;

    for (int c0 = 0; c0 < cnt; c0 += 64) {
        int k = c0 + lane;
        float ap = 0.0f, colr = 0.0f, colg = 0.0f, colb = 0.0f;
        if (k < cnt) {
            int n = list[k];
            float4 a4 = A_uns[n];
            float4 b4 = B_uns[n];
            colb = C_uns[n];
            colr = b4.z; colg = b4.w;

            float ddx = a4.x - px;
            float ddy = a4.y - py;
            float pw = -0.5f * (a4.z * ddx * ddx + b4.x * ddy * ddy) - a4.w * ddx * ddy;
            pw = fminf(pw, 0.0f);
            ap = b4.y * __expf(pw);
            ap = fminf(ap, 0.99f);
            ap = (ap >= (1.0f / 255.0f)) ? ap : 0.0f;
        }

        // all-transparent chunk contributes exactly nothing (f=1 identity) — skip
        if (__ballot(ap > 0.0f) == 0ull) continue;

        float f = 1.0f - ap;
        // inclusive prefix product across 64 lanes (Hillis-Steele)
        float incl = f;
        #pragma unroll
        for (int d = 1; d < 64; d <<= 1) {
            float v = __shfl_up(incl, d, 64);
            if (lane >= d) incl *= v;
        }
        float excl = __shfl_up(incl, 1, 64);
        if (lane == 0) excl = 1.0f;

        float tau = carry * excl;
        float wgt = (tau > 1e-4f) ? ap * tau : 0.0f;
        accr += colr * wgt;
        accg += colg * wgt;
        accb += colb * wgt;

        carry *= __shfl(incl, 63, 64);       // wave-uniform chunk transmittance
        if (carry <= 1e-4f) break;           // exact early exit (factors <= 1)
    }

    // wave reduction of the three accumulators
    #pragma unroll
    for (int d = 32; d >= 1; d >>= 1) {
        accr += __shfl_xor(accr, d, 64);
        accg += __shfl_xor(accg, d, 64);
        accb += __shfl_xor(accb, d, 64);
    }
    if (lane == 0) {
        img[0 * NPIX + p] = accr;
        img[1 * NPIX + p] = accg;
        img[2 * NPIX + p] = accb;
    }
}

extern "C" void kernel_launch(void* const* d_in, const int* in_sizes, int n_in,
                              void* d_out, int out_size, void* d_ws, size_t ws_size,
                              hipStream_t stream) {
    const float* pws        = (const float*)d_in[0];
    const float* low_shs    = (const float*)d_in[1];
    const float* high_shs   = (const float*)d_in[2];
    const float* alphas_raw = (const float*)d_in[3];
    const float* scales_raw = (const float*)d_in[4];
    const float* rots_raw   = (const float*)d_in[5];
    // d_in[6] = us (unused by the forward pass)
    const float* Rcw        = (const float*)d_in[7];
    const float* tcw        = (const float*)d_in[8];
    const float* cam        = (const float*)d_in[9];

    float* out_img   = (float*)d_out;             // 3*96*96
    float* out_areas = (float*)d_out + 3 * NPIX;  // N*2

    // workspace layout (bytes); ws_size is 256 MB — we use ~1.3 MB
    char* ws = (char*)d_ws;
    float*  depth_ws = (float*) (ws + 0);          // 16 KB
    int*    rank_ws  = (int*)   (ws + 16384);      // 16 KB
    float4* A_uns    = (float4*)(ws + 32768);      // 64 KB
    float4* B_uns    = (float4*)(ws + 98304);      // 64 KB
    float*  C_uns    = (float*) (ws + 163840);     // 16 KB
    float4* D_uns    = (float4*)(ws + 180224);     // 64 KB
    int*    tile_cnt = (int*)   (ws + 245760);     // 256 B
    int*    tile_list= (int*)   (ws + 247808);     // 64*4096*4 = 1 MB

    gs_prep<<<GS_N / 256, 256, 0, stream>>>(
        pws, low_shs, high_shs, alphas_raw, scales_raw, rots_raw, Rcw, tcw, cam,
        out_areas, depth_ws, rank_ws, A_uns, B_uns, C_uns, D_uns);

    gs_rank_partial<<<256, 256, 0, stream>>>(depth_ws, rank_ws);

    gs_bin2<<<NTILES, 256, 0, stream>>>(rank_ws, D_uns, tile_list, tile_cnt);

    gs_raster<<<NTILES * WAVES_PER_TILE, 256, 0, stream>>>(
        A_uns, B_uns, C_uns, tile_list, tile_cnt, out_img);
}

// Round 4
// 96.259 us; speedup vs baseline: 1.5716x; 1.0571x over previous
//
#include <hip/hip_runtime.h>
#include <hip/hip_bf16.h>
#include <math.h>

#define GS_N 4096
#define IMG_H 96
#define IMG_W 96
#define NPIX (IMG_H * IMG_W)
#define TILE_PX 12
#define TILES_X 8
#define NTILES (TILES_X * TILES_X)          // 64 tiles of 12x12 px
#define WAVES_PER_TILE 36                    // 144 px / 4 waves-per-block

// SH constants
#define SH_C0 0.28209479177387814f
#define SH_C1 0.4886025119029199f
__device__ __constant__ float kC2[5] = {1.0925484305920792f, -1.0925484305920792f, 0.31539156525252005f, -1.0925484305920792f, 0.5462742152960396f};
__device__ __constant__ float kC3[7] = {-0.5900435899266435f, 2.890611442640554f, -0.4570457994644658f, 0.3731763325901154f, -0.4570457994644658f, 1.445305721320277f, -0.5900435899266435f};

// -------------------- Kernel 1: per-gaussian preprocessing --------------------
__global__ __launch_bounds__(256) void gs_prep(
    const float* __restrict__ pws, const float* __restrict__ low_shs,
    const float* __restrict__ high_shs, const float* __restrict__ alphas_raw,
    const float* __restrict__ scales_raw, const float* __restrict__ rots_raw,
    const float* __restrict__ Rcw, const float* __restrict__ tcw,
    const float* __restrict__ cam,
    float* __restrict__ areas_out,      // N*2, original order (part of d_out)
    float* __restrict__ depth_ws,       // N
    int*   __restrict__ rank_ws,        // N (zeroed here for the atomic partial-rank)
    float4* __restrict__ A_uns,         // {ux, uy, ci0, ci1}
    float4* __restrict__ B_uns,         // {ci2, alpha_eff, colR, colG}
    float* __restrict__ C_uns,          // colB
    float4* __restrict__ D_uns,         // {ux, uy, rx, ry} bbox (rx<0 => culled)
    unsigned long long* __restrict__ mask_ws)  // 64 tiles * 64 words, zeroed here
{
    int i = blockIdx.x * 256 + threadIdx.x;
    if (i >= GS_N) return;

    rank_ws[i] = 0;     // ws is poisoned 0xAA before every launch; zero it here
    mask_ws[i] = 0ull;  // exactly 4096 mask words; atomicOr'd two kernels later

    float fx = cam[0], fy = cam[1], cxi = cam[2], cyi = cam[3];
    float R0 = Rcw[0], R1 = Rcw[1], R2 = Rcw[2];
    float R3 = Rcw[3], R4 = Rcw[4], R5 = Rcw[5];
    float R6 = Rcw[6], R7 = Rcw[7], R8 = Rcw[8];
    float t0 = tcw[0], t1 = tcw[1], t2 = tcw[2];

    float pwx = pws[3*i+0], pwy = pws[3*i+1], pwz = pws[3*i+2];

    // camera-space point: pcs = Rcw @ pw + tcw
    float pcx = R0*pwx + R1*pwy + R2*pwz + t0;
    float pcy = R3*pwx + R4*pwy + R5*pwz + t1;
    float pcz = R6*pwx + R7*pwy + R8*pwz + t2;

    float depth = pcz;
    float zs = (depth > 1e-6f) ? depth : 1e-6f;

    float ux = fx * pcx / zs + cxi;
    float uy = fy * pcy / zs + cyi;

    float alpha = 1.0f / (1.0f + expf(-alphas_raw[i]));

    float s0 = expf(scales_raw[3*i+0]);
    float s1 = expf(scales_raw[3*i+1]);
    float s2 = expf(scales_raw[3*i+2]);

    float qw = rots_raw[4*i+0], qx = rots_raw[4*i+1], qy = rots_raw[4*i+2], qz = rots_raw[4*i+3];
    float qn = sqrtf(qw*qw + qx*qx + qy*qy + qz*qz);
    qw /= qn; qx /= qn; qy /= qn; qz /= qn;

    float r00 = 1.0f - 2.0f*(qy*qy + qz*qz);
    float r01 = 2.0f*(qx*qy - qw*qz);
    float r02 = 2.0f*(qx*qz + qw*qy);
    float r10 = 2.0f*(qx*qy + qw*qz);
    float r11 = 1.0f - 2.0f*(qx*qx + qz*qz);
    float r12 = 2.0f*(qy*qz - qw*qx);
    float r20 = 2.0f*(qx*qz - qw*qy);
    float r21 = 2.0f*(qy*qz + qw*qx);
    float r22 = 1.0f - 2.0f*(qx*qx + qy*qy);

    // M = Rot * diag(scale)
    float m00 = r00*s0, m01 = r01*s1, m02 = r02*s2;
    float m10 = r10*s0, m11 = r11*s1, m12 = r12*s2;
    float m20 = r20*s0, m21 = r21*s1, m22 = r22*s2;

    // cov3d = M M^T (symmetric)
    float V00 = m00*m00 + m01*m01 + m02*m02;
    float V01 = m00*m10 + m01*m11 + m02*m12;
    float V02 = m00*m20 + m01*m21 + m02*m22;
    float V11 = m10*m10 + m11*m11 + m12*m12;
    float V12 = m10*m20 + m11*m21 + m12*m22;
    float V22 = m20*m20 + m21*m21 + m22*m22;

    float limx = 1.3f * ((float)IMG_W / (2.0f * fx));
    float limy = 1.3f * ((float)IMG_H / (2.0f * fy));
    float xzr = pcx / zs, yzr = pcy / zs;
    float txv = fminf(fmaxf(xzr, -limx), limx) * zs;
    float tyv = fminf(fmaxf(yzr, -limy), limy) * zs;

    float J00 = fx / zs, J02 = -fx * txv / (zs * zs);
    float J11 = fy / zs, J12 = -fy * tyv / (zs * zs);

    // T = J @ Rcw  (2x3)
    float T00 = J00*R0 + J02*R6, T01 = J00*R1 + J02*R7, T02 = J00*R2 + J02*R8;
    float T10 = J11*R3 + J12*R6, T11 = J11*R4 + J12*R7, T12 = J11*R5 + J12*R8;

    // TW = T @ cov3d
    float TW00 = T00*V00 + T01*V01 + T02*V02;
    float TW01 = T00*V01 + T01*V11 + T02*V12;
    float TW02 = T00*V02 + T01*V12 + T02*V22;
    float TW10 = T10*V00 + T11*V01 + T12*V02;
    float TW11 = T10*V01 + T11*V11 + T12*V12;
    float TW12 = T10*V02 + T11*V12 + T12*V22;

    // cov2d = TW @ T^T
    float c00 = TW00*T00 + TW01*T01 + TW02*T02;
    float c01 = TW00*T10 + TW01*T11 + TW02*T12;
    float c11 = TW10*T10 + TW11*T11 + TW12*T12;

    float a  = c00 + 0.3f;
    float b  = c01;
    float cc = c11 + 0.3f;
    float det = a * cc - b * b;
    float ci0 = cc / det;
    float ci1 = -b / det;
    float ci2 = a / det;

    float mid = 0.5f * (a + cc);
    float lam = mid + sqrtf(fmaxf(mid * mid - det, 0.1f));
    float radius = ceilf(3.0f * sqrtf(lam));
    areas_out[2*i + 0] = radius;
    areas_out[2*i + 1] = radius;

    // view dir: twc = -(Rcw^T @ tcw)
    float twcx = -(R0*t0 + R3*t1 + R6*t2);
    float twcy = -(R1*t0 + R4*t1 + R7*t2);
    float twcz = -(R2*t0 + R5*t1 + R8*t2);
    float dx = pwx - twcx, dy = pwy - twcy, dz = pwz - twcz;
    float dn = sqrtf(dx*dx + dy*dy + dz*dz);
    dx /= dn; dy /= dn; dz /= dn;

    float xx = dx*dx, yy = dy*dy, zz = dz*dz;
    float xy = dx*dy, yz = dy*dz, xz = dx*dz;

    // SH basis (16)
    float bas0  = SH_C0;
    float bas1  = -SH_C1 * dy;
    float bas2  =  SH_C1 * dz;
    float bas3  = -SH_C1 * dx;
    float bas4  = kC2[0] * xy;
    float bas5  = kC2[1] * yz;
    float bas6  = kC2[2] * (2.0f*zz - xx - yy);
    float bas7  = kC2[3] * xz;
    float bas8  = kC2[4] * (xx - yy);
    float bas9  = kC3[0] * dy * (3.0f*xx - yy);
    float bas10 = kC3[1] * xy * dz;
    float bas11 = kC3[2] * dy * (4.0f*zz - xx - yy);
    float bas12 = kC3[3] * dz * (2.0f*zz - 3.0f*xx - 3.0f*yy);
    float bas13 = kC3[4] * dx * (4.0f*zz - xx - yy);
    float bas14 = kC3[5] * dz * (xx - yy);
    float bas15 = kC3[6] * dx * (xx - 3.0f*yy);

    float col[3];
    #pragma unroll
    for (int c = 0; c < 3; ++c) {
        const float* hs = high_shs + 45*i + c;
        float acc = bas0 * low_shs[3*i + c];
        acc += bas1  * hs[0*3];
        acc += bas2  * hs[1*3];
        acc += bas3  * hs[2*3];
        acc += bas4  * hs[3*3];
        acc += bas5  * hs[4*3];
        acc += bas6  * hs[5*3];
        acc += bas7  * hs[6*3];
        acc += bas8  * hs[7*3];
        acc += bas9  * hs[8*3];
        acc += bas10 * hs[9*3];
        acc += bas11 * hs[10*3];
        acc += bas12 * hs[11*3];
        acc += bas13 * hs[12*3];
        acc += bas14 * hs[13*3];
        acc += bas15 * hs[14*3];
        col[c] = fmaxf(acc + 0.5f, 0.0f);
    }

    bool valid = depth > 0.2f;
    float al_eff = valid ? alpha : 0.0f;   // alpha=0 => ap=0 => same as reference masking

    // Visibility ellipse: ap>=1/255 <=> Q <= T, T = ln(255*alpha).
    // Max extent of {Q<=T} along x is sqrt(2*T*Cxx) (C = dilated covariance).
    // +1e-4 margin makes the cull strictly conservative vs float rounding.
    float Tthr = __logf(255.0f * al_eff) + 1e-4f;
    float rx = (Tthr > 0.0f) ? sqrtf(2.0f * Tthr * a)  : -1.0f;
    float ry = (Tthr > 0.0f) ? sqrtf(2.0f * Tthr * cc) : -1.0f;

    depth_ws[i] = depth;
    A_uns[i] = make_float4(ux, uy, ci0, ci1);
    B_uns[i] = make_float4(ci2, al_eff, col[0], col[1]);
    C_uns[i] = col[2];
    D_uns[i] = make_float4(ux, uy, rx, ry);
}

// -------------------- Kernel 2: tiled partial rank (16x16 tile grid) --------------------
// rank[i] = #{ j : depth[j] < depth[i]  or (depth[j]==depth[i] and j<i) }  (stable argsort)
__global__ __launch_bounds__(256) void gs_rank_partial(
    const float* __restrict__ depth, int* __restrict__ rank_ws)
{
    __shared__ float sd[256];
    int itile = blockIdx.x >> 4;
    int jtile = blockIdx.x & 15;
    int tid = threadIdx.x;
    int i = itile * 256 + tid;

    sd[tid] = depth[jtile * 256 + tid];
    __syncthreads();

    float mg = depth[i];
    int jbase = jtile * 256;
    int rank = 0;
    const float4* s4 = (const float4*)sd;   // broadcast reads: all lanes same addr
    #pragma unroll 16
    for (int jj = 0; jj < 64; ++jj) {
        float4 v = s4[jj];
        int j0 = jbase + jj * 4;
        rank += (v.x < mg || (v.x == mg && (j0+0) < i)) ? 1 : 0;
        rank += (v.y < mg || (v.y == mg && (j0+1) < i)) ? 1 : 0;
        rank += (v.z < mg || (v.z == mg && (j0+2) < i)) ? 1 : 0;
        rank += (v.w < mg || (v.w == mg && (j0+3) < i)) ? 1 : 0;
    }
    atomicAdd(&rank_ws[i], rank);
}

// -------------------- Kernel 3: gather to rank order + per-tile bitmask ---------------
// Barrier-free, 4096 threads. Rank r IS the depth position, so setting bit r in a
// tile's 4096-bit mask encodes that tile's depth-sorted list implicitly.
// Conservative over-inclusion of tiles is bit-exact: extra entries have ap<1/255 for
// every pixel of the tile, are zeroed by the raster, and x*1.0f==x in the product.
__global__ __launch_bounds__(256) void gs_gather_mask(
    const int* __restrict__ rank_ws,
    const float4* __restrict__ A_uns, const float4* __restrict__ B_uns,
    const float* __restrict__ C_uns, const float4* __restrict__ D_uns,
    float4* __restrict__ A_s, float4* __restrict__ B_s, float* __restrict__ C_s,
    unsigned long long* __restrict__ mask_ws)
{
    int i = blockIdx.x * 256 + threadIdx.x;
    int r = rank_ws[i];
    A_s[r] = A_uns[i];
    B_s[r] = B_uns[i];
    C_s[r] = C_uns[i];

    float4 d = D_uns[i];
    if (d.z >= 0.0f) {
        const float inv = 1.0f / (float)TILE_PX;
        // tile tx covered iff  d.x - d.z <= tx*12+11  &&  d.x + d.z >= tx*12
        // widen by 1e-4 tiles (>> fp32 rounding of px coords) — superset is exact.
        int tx0 = max(0, (int)ceilf((d.x - d.z - (float)(TILE_PX - 1)) * inv - 1e-4f));
        int tx1 = min(TILES_X - 1, (int)floorf((d.x + d.z) * inv + 1e-4f));
        int ty0 = max(0, (int)ceilf((d.y - d.w - (float)(TILE_PX - 1)) * inv - 1e-4f));
        int ty1 = min(TILES_X - 1, (int)floorf((d.y + d.w) * inv + 1e-4f));
        unsigned long long bit = 1ull << (r & 63);
        int w = r >> 6;
        for (int ty = ty0; ty <= ty1; ++ty)
            for (int tx = tx0; tx <= tx1; ++tx)
                atomicOr(&mask_ws[(ty * TILES_X + tx) * 64 + w], bit);
    }
}

// -------------------- Kernel 4: mask-compact + wave-per-pixel compositing -----------
// Block = 4 waves = 4 pixels of one tile; 36 blocks per tile. Wave 0 compacts the
// tile's 512 B mask into an LDS ushort list of ranks (ascending = depth order),
// then each wave composites its pixel: lane l evaluates list entry chunk*64+l and a
// shfl_up prefix product of (1-ap) gives exact per-entry transmittance.
__global__ __launch_bounds__(256) void gs_raster(
    const float4* __restrict__ A_s, const float4* __restrict__ B_s,
    const float* __restrict__ C_s,
    const unsigned long long* __restrict__ mask_ws,
    float* __restrict__ img)
{
    __shared__ unsigned short slist[GS_N];   // 8 KB; worst case all gaussians in tile
    __shared__ int scnt;

    int b = blockIdx.x;                    // 64 * 36 = 2304 blocks
    int tile = b / WAVES_PER_TILE;
    int sub  = b - tile * WAVES_PER_TILE;
    int lane = threadIdx.x & 63;
    int wv   = threadIdx.x >> 6;

    // ---- wave 0: compact bitmask -> rank list (ascending word, ascending bit) ----
    if (wv == 0) {
        unsigned long long m = mask_ws[tile * 64 + lane];
        int c = __popcll(m);
        int incl = c;
        #pragma unroll
        for (int d = 1; d < 64; d <<= 1) {
            int v = __shfl_up(incl, d, 64);
            if (lane >= d) incl += v;
        }
        int off = incl - c;                 // exclusive prefix
        int base = lane << 6;
        while (m) {
            int bpos = __builtin_ctzll(m);
            m &= m - 1;
            slist[off++] = (unsigned short)(base + bpos);
        }
        if (lane == 63) scnt = incl;        // total count
    }
    __syncthreads();
    int cnt = scnt;

    int idxp = sub * 4 + wv;               // 0..143 within tile
    int lx = idxp % TILE_PX, ly = idxp / TILE_PX;
    int tx = tile & (TILES_X - 1), ty = tile >> 3;
    int pxi = tx * TILE_PX + lx, pyi = ty * TILE_PX + ly;
    float px = (float)pxi, py = (float)pyi;
    int p = pyi * IMG_W + pxi;

    float carry = 1.0f;
    float accr = 0.0f, accg = 0.0f, accb = 0.0f;

    for (int c0 = 0; c0 < cnt; c0 += 64) {
        int k = c0 + lane;
        float ap = 0.0f, colr = 0.0f, colg = 0.0f, colb = 0.0f;
        if (k < cnt) {
            int n = slist[k];               // rank index into sorted SoA
            float4 a4 = A_s[n];
            float4 b4 = B_s[n];
            colb = C_s[n];
            colr = b4.z; colg = b4.w;

            float ddx = a4.x - px;
            float ddy = a4.y - py;
            float pw = -0.5f * (a4.z * ddx * ddx + b4.x * ddy * ddy) - a4.w * ddx * ddy;
            pw = fminf(pw, 0.0f);
            ap = b4.y * __expf(pw);
            ap = fminf(ap, 0.99f);
            ap = (ap >= (1.0f / 255.0f)) ? ap : 0.0f;
        }

        // all-transparent chunk contributes exactly nothing (f=1 identity) — skip
        if (__ballot(ap > 0.0f) == 0ull) continue;

        float f = 1.0f - ap;
        // inclusive prefix product across 64 lanes (Hillis-Steele)
        float incl = f;
        #pragma unroll
        for (int d = 1; d < 64; d <<= 1) {
            float v = __shfl_up(incl, d, 64);
            if (lane >= d) incl *= v;
        }
        float excl = __shfl_up(incl, 1, 64);
        if (lane == 0) excl = 1.0f;

        float tau = carry * excl;
        float wgt = (tau > 1e-4f) ? ap * tau : 0.0f;
        accr += colr * wgt;
        accg += colg * wgt;
        accb += colb * wgt;

        carry *= __shfl(incl, 63, 64);       // wave-uniform chunk transmittance
        if (carry <= 1e-4f) break;           // exact early exit (factors <= 1)
    }

    // wave reduction of the three accumulators
    #pragma unroll
    for (int d = 32; d >= 1; d >>= 1) {
        accr += __shfl_xor(accr, d, 64);
        accg += __shfl_xor(accg, d, 64);
        accb += __shfl_xor(accb, d, 64);
    }
    if (lane == 0) {
        img[0 * NPIX + p] = accr;
        img[1 * NPIX + p] = accg;
        img[2 * NPIX + p] = accb;
    }
}

extern "C" void kernel_launch(void* const* d_in, const int* in_sizes, int n_in,
                              void* d_out, int out_size, void* d_ws, size_t ws_size,
                              hipStream_t stream) {
    const float* pws        = (const float*)d_in[0];
    const float* low_shs    = (const float*)d_in[1];
    const float* high_shs   = (const float*)d_in[2];
    const float* alphas_raw = (const float*)d_in[3];
    const float* scales_raw = (const float*)d_in[4];
    const float* rots_raw   = (const float*)d_in[5];
    // d_in[6] = us (unused by the forward pass)
    const float* Rcw        = (const float*)d_in[7];
    const float* tcw        = (const float*)d_in[8];
    const float* cam        = (const float*)d_in[9];

    float* out_img   = (float*)d_out;             // 3*96*96
    float* out_areas = (float*)d_out + 3 * NPIX;  // N*2

    // workspace layout (bytes); ws_size is 256 MB — we use ~416 KB
    char* ws = (char*)d_ws;
    float*  depth_ws = (float*) (ws + 0);          // 16 KB
    int*    rank_ws  = (int*)   (ws + 16384);      // 16 KB
    float4* A_uns    = (float4*)(ws + 32768);      // 64 KB
    float4* B_uns    = (float4*)(ws + 98304);      // 64 KB
    float*  C_uns    = (float*) (ws + 163840);     // 16 KB
    float4* D_uns    = (float4*)(ws + 180224);     // 64 KB
    float4* A_s      = (float4*)(ws + 245760);     // 64 KB
    float4* B_s      = (float4*)(ws + 311296);     // 64 KB
    float*  C_s      = (float*) (ws + 376832);     // 16 KB
    unsigned long long* mask_ws = (unsigned long long*)(ws + 393216);  // 32 KB

    gs_prep<<<GS_N / 256, 256, 0, stream>>>(
        pws, low_shs, high_shs, alphas_raw, scales_raw, rots_raw, Rcw, tcw, cam,
        out_areas, depth_ws, rank_ws, A_uns, B_uns, C_uns, D_uns, mask_ws);

    gs_rank_partial<<<256, 256, 0, stream>>>(depth_ws, rank_ws);

    gs_gather_mask<<<GS_N / 256, 256, 0, stream>>>(
        rank_ws, A_uns, B_uns, C_uns, D_uns, A_s, B_s, C_s, mask_ws);

    gs_raster<<<NTILES * WAVES_PER_TILE, 256, 0, stream>>>(
        A_s, B_s, C_s, mask_ws, out_img);
}

// Round 5
// 95.047 us; speedup vs baseline: 1.5917x; 1.0127x over previous
//
#include <hip/hip_runtime.h>
#include <hip/hip_bf16.h>
#include <math.h>

#define GS_N 4096
#define IMG_H 96
#define IMG_W 96
#define NPIX (IMG_H * IMG_W)
#define TILE_PX 12
#define TILES_X 8
#define NTILES (TILES_X * TILES_X)          // 64 tiles of 12x12 px
#define WAVES_PER_TILE 36                    // 144 px / 4 waves-per-block

// SH constants
#define SH_C0 0.28209479177387814f
#define SH_C1 0.4886025119029199f
__device__ __constant__ float kC2[5] = {1.0925484305920792f, -1.0925484305920792f, 0.31539156525252005f, -1.0925484305920792f, 0.5462742152960396f};
__device__ __constant__ float kC3[7] = {-0.5900435899266435f, 2.890611442640554f, -0.4570457994644658f, 0.3731763325901154f, -0.4570457994644658f, 1.445305721320277f, -0.5900435899266435f};

// -------------------- Kernel 1: per-gaussian preprocessing --------------------
__global__ __launch_bounds__(256) void gs_prep(
    const float* __restrict__ pws, const float* __restrict__ low_shs,
    const float* __restrict__ high_shs, const float* __restrict__ alphas_raw,
    const float* __restrict__ scales_raw, const float* __restrict__ rots_raw,
    const float* __restrict__ Rcw, const float* __restrict__ tcw,
    const float* __restrict__ cam,
    float* __restrict__ areas_out,      // N*2, original order (part of d_out)
    float* __restrict__ depth_ws,       // N
    int*   __restrict__ rank_ws,        // N (zeroed here for the atomic partial-rank)
    float4* __restrict__ A_uns,         // {ux, uy, ci0, ci1}
    float4* __restrict__ B_uns,         // {ci2, alpha_eff, colR, colG}
    float* __restrict__ C_uns,          // colB
    float4* __restrict__ D_uns,         // {ux, uy, rx, ry} bbox (rx<0 => culled)
    unsigned long long* __restrict__ mask_ws)  // 64 tiles * 64 words, zeroed here
{
    int i = blockIdx.x * 256 + threadIdx.x;
    if (i >= GS_N) return;

    rank_ws[i] = 0;     // ws is poisoned 0xAA before every launch; zero it here
    mask_ws[i] = 0ull;  // exactly 4096 mask words; atomicOr'd two kernels later

    float fx = cam[0], fy = cam[1], cxi = cam[2], cyi = cam[3];
    float R0 = Rcw[0], R1 = Rcw[1], R2 = Rcw[2];
    float R3 = Rcw[3], R4 = Rcw[4], R5 = Rcw[5];
    float R6 = Rcw[6], R7 = Rcw[7], R8 = Rcw[8];
    float t0 = tcw[0], t1 = tcw[1], t2 = tcw[2];

    float pwx = pws[3*i+0], pwy = pws[3*i+1], pwz = pws[3*i+2];

    // camera-space point: pcs = Rcw @ pw + tcw
    float pcx = R0*pwx + R1*pwy + R2*pwz + t0;
    float pcy = R3*pwx + R4*pwy + R5*pwz + t1;
    float pcz = R6*pwx + R7*pwy + R8*pwz + t2;

    float depth = pcz;
    float zs = (depth > 1e-6f) ? depth : 1e-6f;

    float ux = fx * pcx / zs + cxi;
    float uy = fy * pcy / zs + cyi;

    float alpha = 1.0f / (1.0f + expf(-alphas_raw[i]));

    float s0 = expf(scales_raw[3*i+0]);
    float s1 = expf(scales_raw[3*i+1]);
    float s2 = expf(scales_raw[3*i+2]);

    float qw = rots_raw[4*i+0], qx = rots_raw[4*i+1], qy = rots_raw[4*i+2], qz = rots_raw[4*i+3];
    float qn = sqrtf(qw*qw + qx*qx + qy*qy + qz*qz);
    qw /= qn; qx /= qn; qy /= qn; qz /= qn;

    float r00 = 1.0f - 2.0f*(qy*qy + qz*qz);
    float r01 = 2.0f*(qx*qy - qw*qz);
    float r02 = 2.0f*(qx*qz + qw*qy);
    float r10 = 2.0f*(qx*qy + qw*qz);
    float r11 = 1.0f - 2.0f*(qx*qx + qz*qz);
    float r12 = 2.0f*(qy*qz - qw*qx);
    float r20 = 2.0f*(qx*qz - qw*qy);
    float r21 = 2.0f*(qy*qz + qw*qx);
    float r22 = 1.0f - 2.0f*(qx*qx + qy*qy);

    // M = Rot * diag(scale)
    float m00 = r00*s0, m01 = r01*s1, m02 = r02*s2;
    float m10 = r10*s0, m11 = r11*s1, m12 = r12*s2;
    float m20 = r20*s0, m21 = r21*s1, m22 = r22*s2;

    // cov3d = M M^T (symmetric)
    float V00 = m00*m00 + m01*m01 + m02*m02;
    float V01 = m00*m10 + m01*m11 + m02*m12;
    float V02 = m00*m20 + m01*m21 + m02*m22;
    float V11 = m10*m10 + m11*m11 + m12*m12;
    float V12 = m10*m20 + m11*m21 + m12*m22;
    float V22 = m20*m20 + m21*m21 + m22*m22;

    float limx = 1.3f * ((float)IMG_W / (2.0f * fx));
    float limy = 1.3f * ((float)IMG_H / (2.0f * fy));
    float xzr = pcx / zs, yzr = pcy / zs;
    float txv = fminf(fmaxf(xzr, -limx), limx) * zs;
    float tyv = fminf(fmaxf(yzr, -limy), limy) * zs;

    float J00 = fx / zs, J02 = -fx * txv / (zs * zs);
    float J11 = fy / zs, J12 = -fy * tyv / (zs * zs);

    // T = J @ Rcw  (2x3)
    float T00 = J00*R0 + J02*R6, T01 = J00*R1 + J02*R7, T02 = J00*R2 + J02*R8;
    float T10 = J11*R3 + J12*R6, T11 = J11*R4 + J12*R7, T12 = J11*R5 + J12*R8;

    // TW = T @ cov3d
    float TW00 = T00*V00 + T01*V01 + T02*V02;
    float TW01 = T00*V01 + T01*V11 + T02*V12;
    float TW02 = T00*V02 + T01*V12 + T02*V22;
    float TW10 = T10*V00 + T11*V01 + T12*V02;
    float TW11 = T10*V01 + T11*V11 + T12*V12;
    float TW12 = T10*V02 + T11*V12 + T12*V22;

    // cov2d = TW @ T^T
    float c00 = TW00*T00 + TW01*T01 + TW02*T02;
    float c01 = TW00*T10 + TW01*T11 + TW02*T12;
    float c11 = TW10*T10 + TW11*T11 + TW12*T12;

    float a  = c00 + 0.3f;
    float b  = c01;
    float cc = c11 + 0.3f;
    float det = a * cc - b * b;
    float ci0 = cc / det;
    float ci1 = -b / det;
    float ci2 = a / det;

    float mid = 0.5f * (a + cc);
    float lam = mid + sqrtf(fmaxf(mid * mid - det, 0.1f));
    float radius = ceilf(3.0f * sqrtf(lam));
    areas_out[2*i + 0] = radius;
    areas_out[2*i + 1] = radius;

    // view dir: twc = -(Rcw^T @ tcw)
    float twcx = -(R0*t0 + R3*t1 + R6*t2);
    float twcy = -(R1*t0 + R4*t1 + R7*t2);
    float twcz = -(R2*t0 + R5*t1 + R8*t2);
    float dx = pwx - twcx, dy = pwy - twcy, dz = pwz - twcz;
    float dn = sqrtf(dx*dx + dy*dy + dz*dz);
    dx /= dn; dy /= dn; dz /= dn;

    float xx = dx*dx, yy = dy*dy, zz = dz*dz;
    float xy = dx*dy, yz = dy*dz, xz = dx*dz;

    // SH basis (16)
    float bas0  = SH_C0;
    float bas1  = -SH_C1 * dy;
    float bas2  =  SH_C1 * dz;
    float bas3  = -SH_C1 * dx;
    float bas4  = kC2[0] * xy;
    float bas5  = kC2[1] * yz;
    float bas6  = kC2[2] * (2.0f*zz - xx - yy);
    float bas7  = kC2[3] * xz;
    float bas8  = kC2[4] * (xx - yy);
    float bas9  = kC3[0] * dy * (3.0f*xx - yy);
    float bas10 = kC3[1] * xy * dz;
    float bas11 = kC3[2] * dy * (4.0f*zz - xx - yy);
    float bas12 = kC3[3] * dz * (2.0f*zz - 3.0f*xx - 3.0f*yy);
    float bas13 = kC3[4] * dx * (4.0f*zz - xx - yy);
    float bas14 = kC3[5] * dz * (xx - yy);
    float bas15 = kC3[6] * dx * (xx - 3.0f*yy);

    float col[3];
    #pragma unroll
    for (int c = 0; c < 3; ++c) {
        const float* hs = high_shs + 45*i + c;
        float acc = bas0 * low_shs[3*i + c];
        acc += bas1  * hs[0*3];
        acc += bas2  * hs[1*3];
        acc += bas3  * hs[2*3];
        acc += bas4  * hs[3*3];
        acc += bas5  * hs[4*3];
        acc += bas6  * hs[5*3];
        acc += bas7  * hs[6*3];
        acc += bas8  * hs[7*3];
        acc += bas9  * hs[8*3];
        acc += bas10 * hs[9*3];
        acc += bas11 * hs[10*3];
        acc += bas12 * hs[11*3];
        acc += bas13 * hs[12*3];
        acc += bas14 * hs[13*3];
        acc += bas15 * hs[14*3];
        col[c] = fmaxf(acc + 0.5f, 0.0f);
    }

    bool valid = depth > 0.2f;
    float al_eff = valid ? alpha : 0.0f;   // alpha=0 => ap=0 => same as reference masking

    // Visibility ellipse: ap>=1/255 <=> Q <= T, T = ln(255*alpha).
    // Max extent of {Q<=T} along x is sqrt(2*T*Cxx) (C = dilated covariance).
    // +1e-4 margin makes the cull strictly conservative vs float rounding.
    float Tthr = __logf(255.0f * al_eff) + 1e-4f;
    float rx = (Tthr > 0.0f) ? sqrtf(2.0f * Tthr * a)  : -1.0f;
    float ry = (Tthr > 0.0f) ? sqrtf(2.0f * Tthr * cc) : -1.0f;

    depth_ws[i] = depth;
    A_uns[i] = make_float4(ux, uy, ci0, ci1);
    B_uns[i] = make_float4(ci2, al_eff, col[0], col[1]);
    C_uns[i] = col[2];
    D_uns[i] = make_float4(ux, uy, rx, ry);
}

// -------------------- Kernel 2: tiled partial rank (16x16 tile grid) --------------------
// rank[i] = #{ j : depth[j] < depth[i]  or (depth[j]==depth[i] and j<i) }  (stable argsort)
__global__ __launch_bounds__(256) void gs_rank_partial(
    const float* __restrict__ depth, int* __restrict__ rank_ws)
{
    __shared__ float sd[256];
    int itile = blockIdx.x >> 4;
    int jtile = blockIdx.x & 15;
    int tid = threadIdx.x;
    int i = itile * 256 + tid;

    sd[tid] = depth[jtile * 256 + tid];
    __syncthreads();

    float mg = depth[i];
    int jbase = jtile * 256;
    int rank = 0;
    const float4* s4 = (const float4*)sd;   // broadcast reads: all lanes same addr
    #pragma unroll 16
    for (int jj = 0; jj < 64; ++jj) {
        float4 v = s4[jj];
        int j0 = jbase + jj * 4;
        rank += (v.x < mg || (v.x == mg && (j0+0) < i)) ? 1 : 0;
        rank += (v.y < mg || (v.y == mg && (j0+1) < i)) ? 1 : 0;
        rank += (v.z < mg || (v.z == mg && (j0+2) < i)) ? 1 : 0;
        rank += (v.w < mg || (v.w == mg && (j0+3) < i)) ? 1 : 0;
    }
    atomicAdd(&rank_ws[i], rank);
}

// -------------------- Kernel 3: gather to rank order + per-tile bitmask ---------------
// Barrier-free, 4096 threads. Rank r IS the depth position, so setting bit r in a
// tile's 4096-bit mask encodes that tile's depth-sorted list implicitly.
// Conservative over-inclusion of tiles is bit-exact: extra entries have ap<1/255 for
// every pixel of the tile, are zeroed by the raster, and x*1.0f==x in the product.
__global__ __launch_bounds__(256) void gs_gather_mask(
    const int* __restrict__ rank_ws,
    const float4* __restrict__ A_uns, const float4* __restrict__ B_uns,
    const float* __restrict__ C_uns, const float4* __restrict__ D_uns,
    float4* __restrict__ A_s, float4* __restrict__ B_s, float* __restrict__ C_s,
    unsigned long long* __restrict__ mask_ws)
{
    int i = blockIdx.x * 256 + threadIdx.x;
    int r = rank_ws[i];
    A_s[r] = A_uns[i];
    B_s[r] = B_uns[i];
    C_s[r] = C_uns[i];

    float4 d = D_uns[i];
    if (d.z >= 0.0f) {
        const float inv = 1.0f / (float)TILE_PX;
        // tile tx covered iff  d.x - d.z <= tx*12+11  &&  d.x + d.z >= tx*12
        // widen by 1e-4 tiles (>> fp32 rounding of px coords) — superset is exact.
        int tx0 = max(0, (int)ceilf((d.x - d.z - (float)(TILE_PX - 1)) * inv - 1e-4f));
        int tx1 = min(TILES_X - 1, (int)floorf((d.x + d.z) * inv + 1e-4f));
        int ty0 = max(0, (int)ceilf((d.y - d.w - (float)(TILE_PX - 1)) * inv - 1e-4f));
        int ty1 = min(TILES_X - 1, (int)floorf((d.y + d.w) * inv + 1e-4f));
        unsigned long long bit = 1ull << (r & 63);
        int w = r >> 6;
        for (int ty = ty0; ty <= ty1; ++ty)
            for (int tx = tx0; tx <= tx1; ++tx)
                atomicOr(&mask_ws[(ty * TILES_X + tx) * 64 + w], bit);
    }
}

// -------------------- Kernel 4: per-tile dense expansion --------------------
// One block per tile. Wave 0 compacts the tile's 4096-bit mask into an LDS rank
// list (ascending = depth order); then all 256 threads copy the sorted SoA into a
// DENSE per-tile stream. The one-time sparse gather happens here (once per tile),
// so the 144 pixel-waves of the raster read fully-coalesced consecutive float4s.
__global__ __launch_bounds__(256) void gs_expand(
    const unsigned long long* __restrict__ mask_ws,
    const float4* __restrict__ A_s, const float4* __restrict__ B_s,
    const float* __restrict__ C_s,
    float4* __restrict__ E_A, float4* __restrict__ E_B, float* __restrict__ E_C,
    int* __restrict__ tile_cnt)
{
    __shared__ unsigned short slist[GS_N];   // 8 KB
    __shared__ int scnt;

    int tile = blockIdx.x;
    int tid = threadIdx.x;
    int lane = tid & 63, wv = tid >> 6;

    if (wv == 0) {
        unsigned long long m = mask_ws[tile * 64 + lane];
        int c = __popcll(m);
        int incl = c;
        #pragma unroll
        for (int d = 1; d < 64; d <<= 1) {
            int v = __shfl_up(incl, d, 64);
            if (lane >= d) incl += v;
        }
        int off = incl - c;                 // exclusive prefix
        int base = lane << 6;
        while (m) {
            int bpos = __builtin_ctzll(m);
            m &= m - 1;
            slist[off++] = (unsigned short)(base + bpos);
        }
        if (lane == 63) { scnt = incl; tile_cnt[tile] = incl; }
    }
    __syncthreads();
    int cnt = scnt;

    float4* tA = E_A + tile * GS_N;
    float4* tB = E_B + tile * GS_N;
    float*  tC = E_C + tile * GS_N;
    for (int k = tid; k < cnt; k += 256) {
        int n = slist[k];
        tA[k] = A_s[n];
        tB[k] = B_s[n];
        tC[k] = C_s[n];
    }
}

// -------------------- Kernel 5: wave-per-pixel compositing over dense stream --------
// Block = 4 waves = 4 pixels of one tile; 36 blocks per tile. Lane l evaluates dense
// entry chunk*64+l (coalesced float4 loads, no gather, no LDS); shfl_up prefix
// product of (1-ap) gives exact per-entry transmittance.
__global__ __launch_bounds__(256) void gs_raster(
    const float4* __restrict__ E_A, const float4* __restrict__ E_B,
    const float* __restrict__ E_C,
    const int* __restrict__ tile_cnt,
    float* __restrict__ img)
{
    int b = blockIdx.x;                    // 64 * 36 = 2304 blocks
    int tile = b / WAVES_PER_TILE;
    int sub  = b - tile * WAVES_PER_TILE;
    int lane = threadIdx.x & 63;
    int wv   = threadIdx.x >> 6;

    int idxp = sub * 4 + wv;               // 0..143 within tile
    int lx = idxp % TILE_PX, ly = idxp / TILE_PX;
    int tx = tile & (TILES_X - 1), ty = tile >> 3;
    int pxi = tx * TILE_PX + lx, pyi = ty * TILE_PX + ly;
    float px = (float)pxi, py = (float)pyi;
    int p = pyi * IMG_W + pxi;

    int cnt = tile_cnt[tile];
    const float4* tA = E_A + tile * GS_N;
    const float4* tB = E_B + tile * GS_N;
    const float*  tC = E_C + tile * GS_N;

    float carry = 1.0f;
    float accr = 0.0f, accg = 0.0f, accb = 0.0f;

    for (int c0 = 0; c0 < cnt; c0 += 64) {
        int k = c0 + lane;
        float ap = 0.0f, colr = 0.0f, colg = 0.0f, colb = 0.0f;
        if (k < cnt) {
            float4 a4 = tA[k];              // dense, coalesced
            float4 b4 = tB[k];
            colb = tC[k];
            colr = b4.z; colg = b4.w;

            float ddx = a4.x - px;
            float ddy = a4.y - py;
            float pw = -0.5f * (a4.z * ddx * ddx + b4.x * ddy * ddy) - a4.w * ddx * ddy;
            pw = fminf(pw, 0.0f);
            ap = b4.y * __expf(pw);
            ap = fminf(ap, 0.99f);
            ap = (ap >= (1.0f / 255.0f)) ? ap : 0.0f;
        }

        // all-transparent chunk contributes exactly nothing (f=1 identity) — skip
        if (__ballot(ap > 0.0f) == 0ull) continue;

        float f = 1.0f - ap;
        // inclusive prefix product across 64 lanes (Hillis-Steele)
        float incl = f;
        #pragma unroll
        for (int d = 1; d < 64; d <<= 1) {
            float v = __shfl_up(incl, d, 64);
            if (lane >= d) incl *= v;
        }
        float excl = __shfl_up(incl, 1, 64);
        if (lane == 0) excl = 1.0f;

        float tau = carry * excl;
        float wgt = (tau > 1e-4f) ? ap * tau : 0.0f;
        accr += colr * wgt;
        accg += colg * wgt;
        accb += colb * wgt;

        carry *= __shfl(incl, 63, 64);       // wave-uniform chunk transmittance
        if (carry <= 1e-4f) break;           // exact early exit (factors <= 1)
    }

    // wave reduction of the three accumulators
    #pragma unroll
    for (int d = 32; d >= 1; d >>= 1) {
        accr += __shfl_xor(accr, d, 64);
        accg += __shfl_xor(accg, d, 64);
        accb += __shfl_xor(accb, d, 64);
    }
    if (lane == 0) {
        img[0 * NPIX + p] = accr;
        img[1 * NPIX + p] = accg;
        img[2 * NPIX + p] = accb;
    }
}

extern "C" void kernel_launch(void* const* d_in, const int* in_sizes, int n_in,
                              void* d_out, int out_size, void* d_ws, size_t ws_size,
                              hipStream_t stream) {
    const float* pws        = (const float*)d_in[0];
    const float* low_shs    = (const float*)d_in[1];
    const float* high_shs   = (const float*)d_in[2];
    const float* alphas_raw = (const float*)d_in[3];
    const float* scales_raw = (const float*)d_in[4];
    const float* rots_raw   = (const float*)d_in[5];
    // d_in[6] = us (unused by the forward pass)
    const float* Rcw        = (const float*)d_in[7];
    const float* tcw        = (const float*)d_in[8];
    const float* cam        = (const float*)d_in[9];

    float* out_img   = (float*)d_out;             // 3*96*96
    float* out_areas = (float*)d_out + 3 * NPIX;  // N*2

    // workspace layout (bytes); ws_size is 256 MB — we use ~10 MB
    char* ws = (char*)d_ws;
    float*  depth_ws = (float*) (ws + 0);          // 16 KB
    int*    rank_ws  = (int*)   (ws + 16384);      // 16 KB
    float4* A_uns    = (float4*)(ws + 32768);      // 64 KB
    float4* B_uns    = (float4*)(ws + 98304);      // 64 KB
    float*  C_uns    = (float*) (ws + 163840);     // 16 KB
    float4* D_uns    = (float4*)(ws + 180224);     // 64 KB
    float4* A_s      = (float4*)(ws + 245760);     // 64 KB
    float4* B_s      = (float4*)(ws + 311296);     // 64 KB
    float*  C_s      = (float*) (ws + 376832);     // 16 KB
    unsigned long long* mask_ws = (unsigned long long*)(ws + 393216);  // 32 KB
    float4* E_A      = (float4*)(ws + 425984);     // 64*4096*16 = 4 MB
    float4* E_B      = (float4*)(ws + 4620288);    // 4 MB
    float*  E_C      = (float*) (ws + 8814592);    // 1 MB
    int*    tile_cnt = (int*)   (ws + 9863168);    // 256 B

    gs_prep<<<GS_N / 256, 256, 0, stream>>>(
        pws, low_shs, high_shs, alphas_raw, scales_raw, rots_raw, Rcw, tcw, cam,
        out_areas, depth_ws, rank_ws, A_uns, B_uns, C_uns, D_uns, mask_ws);

    gs_rank_partial<<<256, 256, 0, stream>>>(depth_ws, rank_ws);

    gs_gather_mask<<<GS_N / 256, 256, 0, stream>>>(
        rank_ws, A_uns, B_uns, C_uns, D_uns, A_s, B_s, C_s, mask_ws);

    gs_expand<<<NTILES, 256, 0, stream>>>(
        mask_ws, A_s, B_s, C_s, E_A, E_B, E_C, tile_cnt);

    gs_raster<<<NTILES * WAVES_PER_TILE, 256, 0, stream>>>(
        E_A, E_B, E_C, tile_cnt, out_img);
}

// Round 6
// 93.920 us; speedup vs baseline: 1.6108x; 1.0120x over previous
//
#include <hip/hip_runtime.h>
#include <hip/hip_bf16.h>
#include <math.h>

#define GS_N 4096
#define IMG_H 96
#define IMG_W 96
#define NPIX (IMG_H * IMG_W)
#define TILE_PX 12
#define TILES_X 8
#define NTILES (TILES_X * TILES_X)          // 64 tiles of 12x12 px
#define WAVES_PER_TILE 36                    // 144 px / 4 waves-per-block

// SH constants
#define SH_C0 0.28209479177387814f
#define SH_C1 0.4886025119029199f
__device__ __constant__ float kC2[5] = {1.0925484305920792f, -1.0925484305920792f, 0.31539156525252005f, -1.0925484305920792f, 0.5462742152960396f};
__device__ __constant__ float kC3[7] = {-0.5900435899266435f, 2.890611442640554f, -0.4570457994644658f, 0.3731763325901154f, -0.4570457994644658f, 1.445305721320277f, -0.5900435899266435f};

// Wave64 inclusive prefix PRODUCT via DPP (VALU pipe, ~6x8 cyc dependent chain)
// instead of ds_bpermute __shfl chain (~8x110 cyc). Classic GCN scan idiom:
// row_shr:1,2,4,8 then row_bcast:15 (rows 1,3) and row_bcast:31 (rows 2,3),
// multiplicative identity supplied as the DPP 'old' value for invalid/masked lanes.
__device__ __forceinline__ float wave_incl_prod(float x) {
#if __has_builtin(__builtin_amdgcn_update_dpp)
    const int ONE = __float_as_int(1.0f);
    int t;
    t = __builtin_amdgcn_update_dpp(ONE, __float_as_int(x), 0x111, 0xf, 0xf, false); // row_shr:1
    x *= __int_as_float(t);
    t = __builtin_amdgcn_update_dpp(ONE, __float_as_int(x), 0x112, 0xf, 0xf, false); // row_shr:2
    x *= __int_as_float(t);
    t = __builtin_amdgcn_update_dpp(ONE, __float_as_int(x), 0x114, 0xf, 0xf, false); // row_shr:4
    x *= __int_as_float(t);
    t = __builtin_amdgcn_update_dpp(ONE, __float_as_int(x), 0x118, 0xf, 0xf, false); // row_shr:8
    x *= __int_as_float(t);
    t = __builtin_amdgcn_update_dpp(ONE, __float_as_int(x), 0x142, 0xa, 0xf, false); // row_bcast:15 -> rows 1,3
    x *= __int_as_float(t);
    t = __builtin_amdgcn_update_dpp(ONE, __float_as_int(x), 0x143, 0xc, 0xf, false); // row_bcast:31 -> rows 2,3
    x *= __int_as_float(t);
    return x;
#else
    int lane = threadIdx.x & 63;
    #pragma unroll
    for (int d = 1; d < 64; d <<= 1) {
        float v = __shfl_up(x, d, 64);
        if (lane >= d) x *= v;
    }
    return x;
#endif
}

// -------------------- Kernel 1: per-gaussian preprocessing --------------------
__global__ __launch_bounds__(256) void gs_prep(
    const float* __restrict__ pws, const float* __restrict__ low_shs,
    const float* __restrict__ high_shs, const float* __restrict__ alphas_raw,
    const float* __restrict__ scales_raw, const float* __restrict__ rots_raw,
    const float* __restrict__ Rcw, const float* __restrict__ tcw,
    const float* __restrict__ cam,
    float* __restrict__ areas_out,      // N*2, original order (part of d_out)
    float* __restrict__ depth_ws,       // N
    int*   __restrict__ rank_ws,        // N (zeroed here for the atomic partial-rank)
    float4* __restrict__ A_uns,         // {ux, uy, ci0, ci1}
    float4* __restrict__ B_uns,         // {ci2, alpha_eff, colR, colG}
    float* __restrict__ C_uns,          // colB
    float4* __restrict__ D_uns,         // {ux, uy, rx, ry} bbox (rx<0 => culled)
    unsigned long long* __restrict__ mask_ws)  // 64 tiles * 64 words, zeroed here
{
    int i = blockIdx.x * 256 + threadIdx.x;
    if (i >= GS_N) return;

    rank_ws[i] = 0;     // ws is poisoned 0xAA before every launch; zero it here
    mask_ws[i] = 0ull;  // exactly 4096 mask words; atomicOr'd two kernels later

    float fx = cam[0], fy = cam[1], cxi = cam[2], cyi = cam[3];
    float R0 = Rcw[0], R1 = Rcw[1], R2 = Rcw[2];
    float R3 = Rcw[3], R4 = Rcw[4], R5 = Rcw[5];
    float R6 = Rcw[6], R7 = Rcw[7], R8 = Rcw[8];
    float t0 = tcw[0], t1 = tcw[1], t2 = tcw[2];

    float pwx = pws[3*i+0], pwy = pws[3*i+1], pwz = pws[3*i+2];

    // camera-space point: pcs = Rcw @ pw + tcw
    float pcx = R0*pwx + R1*pwy + R2*pwz + t0;
    float pcy = R3*pwx + R4*pwy + R5*pwz + t1;
    float pcz = R6*pwx + R7*pwy + R8*pwz + t2;

    float depth = pcz;
    float zs = (depth > 1e-6f) ? depth : 1e-6f;

    float ux = fx * pcx / zs + cxi;
    float uy = fy * pcy / zs + cyi;

    float alpha = 1.0f / (1.0f + expf(-alphas_raw[i]));

    float s0 = expf(scales_raw[3*i+0]);
    float s1 = expf(scales_raw[3*i+1]);
    float s2 = expf(scales_raw[3*i+2]);

    float qw = rots_raw[4*i+0], qx = rots_raw[4*i+1], qy = rots_raw[4*i+2], qz = rots_raw[4*i+3];
    float qn = sqrtf(qw*qw + qx*qx + qy*qy + qz*qz);
    qw /= qn; qx /= qn; qy /= qn; qz /= qn;

    float r00 = 1.0f - 2.0f*(qy*qy + qz*qz);
    float r01 = 2.0f*(qx*qy - qw*qz);
    float r02 = 2.0f*(qx*qz + qw*qy);
    float r10 = 2.0f*(qx*qy + qw*qz);
    float r11 = 1.0f - 2.0f*(qx*qx + qz*qz);
    float r12 = 2.0f*(qy*qz - qw*qx);
    float r20 = 2.0f*(qx*qz - qw*qy);
    float r21 = 2.0f*(qy*qz + qw*qx);
    float r22 = 1.0f - 2.0f*(qx*qx + qy*qy);

    // M = Rot * diag(scale)
    float m00 = r00*s0, m01 = r01*s1, m02 = r02*s2;
    float m10 = r10*s0, m11 = r11*s1, m12 = r12*s2;
    float m20 = r20*s0, m21 = r21*s1, m22 = r22*s2;

    // cov3d = M M^T (symmetric)
    float V00 = m00*m00 + m01*m01 + m02*m02;
    float V01 = m00*m10 + m01*m11 + m02*m12;
    float V02 = m00*m20 + m01*m21 + m02*m22;
    float V11 = m10*m10 + m11*m11 + m12*m12;
    float V12 = m10*m20 + m11*m21 + m12*m22;
    float V22 = m20*m20 + m21*m21 + m22*m22;

    float limx = 1.3f * ((float)IMG_W / (2.0f * fx));
    float limy = 1.3f * ((float)IMG_H / (2.0f * fy));
    float xzr = pcx / zs, yzr = pcy / zs;
    float txv = fminf(fmaxf(xzr, -limx), limx) * zs;
    float tyv = fminf(fmaxf(yzr, -limy), limy) * zs;

    float J00 = fx / zs, J02 = -fx * txv / (zs * zs);
    float J11 = fy / zs, J12 = -fy * tyv / (zs * zs);

    // T = J @ Rcw  (2x3)
    float T00 = J00*R0 + J02*R6, T01 = J00*R1 + J02*R7, T02 = J00*R2 + J02*R8;
    float T10 = J11*R3 + J12*R6, T11 = J11*R4 + J12*R7, T12 = J11*R5 + J12*R8;

    // TW = T @ cov3d
    float TW00 = T00*V00 + T01*V01 + T02*V02;
    float TW01 = T00*V01 + T01*V11 + T02*V12;
    float TW02 = T00*V02 + T01*V12 + T02*V22;
    float TW10 = T10*V00 + T11*V01 + T12*V02;
    float TW11 = T10*V01 + T11*V11 + T12*V12;
    float TW12 = T10*V02 + T11*V12 + T12*V22;

    // cov2d = TW @ T^T
    float c00 = TW00*T00 + TW01*T01 + TW02*T02;
    float c01 = TW00*T10 + TW01*T11 + TW02*T12;
    float c11 = TW10*T10 + TW11*T11 + TW12*T12;

    float a  = c00 + 0.3f;
    float b  = c01;
    float cc = c11 + 0.3f;
    float det = a * cc - b * b;
    float ci0 = cc / det;
    float ci1 = -b / det;
    float ci2 = a / det;

    float mid = 0.5f * (a + cc);
    float lam = mid + sqrtf(fmaxf(mid * mid - det, 0.1f));
    float radius = ceilf(3.0f * sqrtf(lam));
    areas_out[2*i + 0] = radius;
    areas_out[2*i + 1] = radius;

    // view dir: twc = -(Rcw^T @ tcw)
    float twcx = -(R0*t0 + R3*t1 + R6*t2);
    float twcy = -(R1*t0 + R4*t1 + R7*t2);
    float twcz = -(R2*t0 + R5*t1 + R8*t2);
    float dx = pwx - twcx, dy = pwy - twcy, dz = pwz - twcz;
    float dn = sqrtf(dx*dx + dy*dy + dz*dz);
    dx /= dn; dy /= dn; dz /= dn;

    float xx = dx*dx, yy = dy*dy, zz = dz*dz;
    float xy = dx*dy, yz = dy*dz, xz = dx*dz;

    // SH basis (16)
    float bas0  = SH_C0;
    float bas1  = -SH_C1 * dy;
    float bas2  =  SH_C1 * dz;
    float bas3  = -SH_C1 * dx;
    float bas4  = kC2[0] * xy;
    float bas5  = kC2[1] * yz;
    float bas6  = kC2[2] * (2.0f*zz - xx - yy);
    float bas7  = kC2[3] * xz;
    float bas8  = kC2[4] * (xx - yy);
    float bas9  = kC3[0] * dy * (3.0f*xx - yy);
    float bas10 = kC3[1] * xy * dz;
    float bas11 = kC3[2] * dy * (4.0f*zz - xx - yy);
    float bas12 = kC3[3] * dz * (2.0f*zz - 3.0f*xx - 3.0f*yy);
    float bas13 = kC3[4] * dx * (4.0f*zz - xx - yy);
    float bas14 = kC3[5] * dz * (xx - yy);
    float bas15 = kC3[6] * dx * (xx - 3.0f*yy);

    float col[3];
    #pragma unroll
    for (int c = 0; c < 3; ++c) {
        const float* hs = high_shs + 45*i + c;
        float acc = bas0 * low_shs[3*i + c];
        acc += bas1  * hs[0*3];
        acc += bas2  * hs[1*3];
        acc += bas3  * hs[2*3];
        acc += bas4  * hs[3*3];
        acc += bas5  * hs[4*3];
        acc += bas6  * hs[5*3];
        acc += bas7  * hs[6*3];
        acc += bas8  * hs[7*3];
        acc += bas9  * hs[8*3];
        acc += bas10 * hs[9*3];
        acc += bas11 * hs[10*3];
        acc += bas12 * hs[11*3];
        acc += bas13 * hs[12*3];
        acc += bas14 * hs[13*3];
        acc += bas15 * hs[14*3];
        col[c] = fmaxf(acc + 0.5f, 0.0f);
    }

    bool valid = depth > 0.2f;
    float al_eff = valid ? alpha : 0.0f;   // alpha=0 => ap=0 => same as reference masking

    // Visibility ellipse: ap>=1/255 <=> Q <= T, T = ln(255*alpha).
    // Max extent of {Q<=T} along x is sqrt(2*T*Cxx) (C = dilated covariance).
    // +1e-4 margin makes the cull strictly conservative vs float rounding.
    float Tthr = __logf(255.0f * al_eff) + 1e-4f;
    float rx = (Tthr > 0.0f) ? sqrtf(2.0f * Tthr * a)  : -1.0f;
    float ry = (Tthr > 0.0f) ? sqrtf(2.0f * Tthr * cc) : -1.0f;

    depth_ws[i] = depth;
    A_uns[i] = make_float4(ux, uy, ci0, ci1);
    B_uns[i] = make_float4(ci2, al_eff, col[0], col[1]);
    C_uns[i] = col[2];
    D_uns[i] = make_float4(ux, uy, rx, ry);
}

// -------------------- Kernel 2: tiled partial rank (16x16 tile grid) --------------------
// rank[i] = #{ j : depth[j] < depth[i]  or (depth[j]==depth[i] and j<i) }  (stable argsort)
__global__ __launch_bounds__(256) void gs_rank_partial(
    const float* __restrict__ depth, int* __restrict__ rank_ws)
{
    __shared__ float sd[256];
    int itile = blockIdx.x >> 4;
    int jtile = blockIdx.x & 15;
    int tid = threadIdx.x;
    int i = itile * 256 + tid;

    sd[tid] = depth[jtile * 256 + tid];
    __syncthreads();

    float mg = depth[i];
    int jbase = jtile * 256;
    int rank = 0;
    const float4* s4 = (const float4*)sd;   // broadcast reads: all lanes same addr
    #pragma unroll 16
    for (int jj = 0; jj < 64; ++jj) {
        float4 v = s4[jj];
        int j0 = jbase + jj * 4;
        rank += (v.x < mg || (v.x == mg && (j0+0) < i)) ? 1 : 0;
        rank += (v.y < mg || (v.y == mg && (j0+1) < i)) ? 1 : 0;
        rank += (v.z < mg || (v.z == mg && (j0+2) < i)) ? 1 : 0;
        rank += (v.w < mg || (v.w == mg && (j0+3) < i)) ? 1 : 0;
    }
    atomicAdd(&rank_ws[i], rank);
}

// -------------------- Kernel 3: inverse permutation + per-tile bitmask ---------------
// Barrier-free, 4096 threads. inv[r] = i gives rank->original mapping (expand gathers
// through it, so the old A_s/B_s/C_s sorted copies are gone). Setting bit r in a
// tile's 4096-bit mask encodes that tile's depth-sorted list implicitly.
// Conservative over-inclusion of tiles is bit-exact: extra entries have ap<1/255 for
// every pixel of the tile, are zeroed by the raster, and x*1.0f==x in the product.
__global__ __launch_bounds__(256) void gs_gather_mask(
    const int* __restrict__ rank_ws,
    const float4* __restrict__ D_uns,
    int* __restrict__ inv_ws,
    unsigned long long* __restrict__ mask_ws)
{
    int i = blockIdx.x * 256 + threadIdx.x;
    int r = rank_ws[i];
    inv_ws[r] = i;

    float4 d = D_uns[i];
    if (d.z >= 0.0f) {
        const float inv = 1.0f / (float)TILE_PX;
        // tile tx covered iff  d.x - d.z <= tx*12+11  &&  d.x + d.z >= tx*12
        // widen by 1e-4 tiles (>> fp32 rounding of px coords) — superset is exact.
        int tx0 = max(0, (int)ceilf((d.x - d.z - (float)(TILE_PX - 1)) * inv - 1e-4f));
        int tx1 = min(TILES_X - 1, (int)floorf((d.x + d.z) * inv + 1e-4f));
        int ty0 = max(0, (int)ceilf((d.y - d.w - (float)(TILE_PX - 1)) * inv - 1e-4f));
        int ty1 = min(TILES_X - 1, (int)floorf((d.y + d.w) * inv + 1e-4f));
        unsigned long long bit = 1ull << (r & 63);
        int w = r >> 6;
        for (int ty = ty0; ty <= ty1; ++ty)
            for (int tx = tx0; tx <= tx1; ++tx)
                atomicOr(&mask_ws[(ty * TILES_X + tx) * 64 + w], bit);
    }
}

// -------------------- Kernel 4: per-tile dense expansion --------------------
// One block per tile. Wave 0 compacts the tile's 4096-bit mask into an LDS rank
// list (ascending = depth order); then all 256 threads gather the original-order
// SoA through inv_ws into a DENSE per-tile stream, read coalesced by the raster.
__global__ __launch_bounds__(256) void gs_expand(
    const unsigned long long* __restrict__ mask_ws,
    const int* __restrict__ inv_ws,
    const float4* __restrict__ A_uns, const float4* __restrict__ B_uns,
    const float* __restrict__ C_uns,
    float4* __restrict__ E_A, float4* __restrict__ E_B, float* __restrict__ E_C,
    int* __restrict__ tile_cnt)
{
    __shared__ unsigned short slist[GS_N];   // 8 KB
    __shared__ int scnt;

    int tile = blockIdx.x;
    int tid = threadIdx.x;
    int lane = tid & 63, wv = tid >> 6;

    if (wv == 0) {
        unsigned long long m = mask_ws[tile * 64 + lane];
        int c = __popcll(m);
        int incl = c;
        #pragma unroll
        for (int d = 1; d < 64; d <<= 1) {
            int v = __shfl_up(incl, d, 64);
            if (lane >= d) incl += v;
        }
        int off = incl - c;                 // exclusive prefix
        int base = lane << 6;
        while (m) {
            int bpos = __builtin_ctzll(m);
            m &= m - 1;
            slist[off++] = (unsigned short)(base + bpos);
        }
        if (lane == 63) { scnt = incl; tile_cnt[tile] = incl; }
    }
    __syncthreads();
    int cnt = scnt;

    float4* tA = E_A + tile * GS_N;
    float4* tB = E_B + tile * GS_N;
    float*  tC = E_C + tile * GS_N;
    for (int k = tid; k < cnt; k += 256) {
        int n = inv_ws[slist[k]];          // rank -> original index
        tA[k] = A_uns[n];
        tB[k] = B_uns[n];
        tC[k] = C_uns[n];
    }
}

// -------------------- Kernel 5: wave-per-pixel compositing, DPP scan, 128/chunk -----
// Block = 4 waves = 4 pixels of one tile; 36 blocks per tile. Lane l evaluates dense
// entries 2l and 2l+1 of each 128-entry chunk; the wave-level prefix product runs on
// the VALU via DPP (wave_incl_prod) instead of an 8-deep ds_bpermute chain. Exact:
// tau(2l) = carry*excl_l, tau(2l+1) = tau(2l)*(1-ap(2l)); per-entry 1e-4 cutoff kept.
__global__ __launch_bounds__(256) void gs_raster(
    const float4* __restrict__ E_A, const float4* __restrict__ E_B,
    const float* __restrict__ E_C,
    const int* __restrict__ tile_cnt,
    float* __restrict__ img)
{
    int b = blockIdx.x;                    // 64 * 36 = 2304 blocks
    int tile = b / WAVES_PER_TILE;
    int sub  = b - tile * WAVES_PER_TILE;
    int lane = threadIdx.x & 63;
    int wv   = threadIdx.x >> 6;

    int idxp = sub * 4 + wv;               // 0..143 within tile
    int lx = idxp % TILE_PX, ly = idxp / TILE_PX;
    int tx = tile & (TILES_X - 1), ty = tile >> 3;
    int pxi = tx * TILE_PX + lx, pyi = ty * TILE_PX + ly;
    float px = (float)pxi, py = (float)pyi;
    int p = pyi * IMG_W + pxi;

    int cnt = tile_cnt[tile];
    const float4* tA = E_A + tile * GS_N;
    const float4* tB = E_B + tile * GS_N;
    const float*  tC = E_C + tile * GS_N;

    float carry = 1.0f;
    float accr = 0.0f, accg = 0.0f, accb = 0.0f;

    for (int c0 = 0; c0 < cnt; c0 += 128) {
        int k0 = c0 + (lane << 1);
        float ap0 = 0.0f, r0 = 0.0f, g0 = 0.0f, b0 = 0.0f;
        float ap1 = 0.0f, r1 = 0.0f, g1 = 0.0f, b1 = 0.0f;
        if (k0 < cnt) {
            float4 a4 = tA[k0];
            float4 b4 = tB[k0];
            b0 = tC[k0]; r0 = b4.z; g0 = b4.w;
            float ddx = a4.x - px, ddy = a4.y - py;
            float pw = -0.5f * (a4.z * ddx * ddx + b4.x * ddy * ddy) - a4.w * ddx * ddy;
            pw = fminf(pw, 0.0f);
            ap0 = b4.y * __expf(pw);
            ap0 = fminf(ap0, 0.99f);
            ap0 = (ap0 >= (1.0f / 255.0f)) ? ap0 : 0.0f;
        }
        if (k0 + 1 < cnt) {
            float4 a4 = tA[k0 + 1];
            float4 b4 = tB[k0 + 1];
            b1 = tC[k0 + 1]; r1 = b4.z; g1 = b4.w;
            float ddx = a4.x - px, ddy = a4.y - py;
            float pw = -0.5f * (a4.z * ddx * ddx + b4.x * ddy * ddy) - a4.w * ddx * ddy;
            pw = fminf(pw, 0.0f);
            ap1 = b4.y * __expf(pw);
            ap1 = fminf(ap1, 0.99f);
            ap1 = (ap1 >= (1.0f / 255.0f)) ? ap1 : 0.0f;
        }

        // all-transparent chunk contributes exactly nothing (f=1 identity) — skip
        if (__ballot(ap0 > 0.0f || ap1 > 0.0f) == 0ull) continue;

        float f0 = 1.0f - ap0;
        float f1 = 1.0f - ap1;
        float incl = wave_incl_prod(f0 * f1);    // DPP, VALU-pipe scan
        float excl = __shfl_up(incl, 1, 64);     // one LDS-routed op per chunk
        excl = (lane == 0) ? 1.0f : excl;

        float tau0 = carry * excl;
        float tau1 = tau0 * f0;
        float w0 = (tau0 > 1e-4f) ? ap0 * tau0 : 0.0f;
        float w1 = (tau1 > 1e-4f) ? ap1 * tau1 : 0.0f;
        accr += r0 * w0 + r1 * w1;
        accg += g0 * w0 + g1 * w1;
        accb += b0 * w0 + b1 * w1;

        carry *= __shfl(incl, 63, 64);       // wave-uniform chunk transmittance
        if (carry <= 1e-4f) break;           // exact early exit (factors <= 1)
    }

    // wave reduction of the three accumulators
    #pragma unroll
    for (int d = 32; d >= 1; d >>= 1) {
        accr += __shfl_xor(accr, d, 64);
        accg += __shfl_xor(accg, d, 64);
        accb += __shfl_xor(accb, d, 64);
    }
    if (lane == 0) {
        img[0 * NPIX + p] = accr;
        img[1 * NPIX + p] = accg;
        img[2 * NPIX + p] = accb;
    }
}

extern "C" void kernel_launch(void* const* d_in, const int* in_sizes, int n_in,
                              void* d_out, int out_size, void* d_ws, size_t ws_size,
                              hipStream_t stream) {
    const float* pws        = (const float*)d_in[0];
    const float* low_shs    = (const float*)d_in[1];
    const float* high_shs   = (const float*)d_in[2];
    const float* alphas_raw = (const float*)d_in[3];
    const float* scales_raw = (const float*)d_in[4];
    const float* rots_raw   = (const float*)d_in[5];
    // d_in[6] = us (unused by the forward pass)
    const float* Rcw        = (const float*)d_in[7];
    const float* tcw        = (const float*)d_in[8];
    const float* cam        = (const float*)d_in[9];

    float* out_img   = (float*)d_out;             // 3*96*96
    float* out_areas = (float*)d_out + 3 * NPIX;  // N*2

    // workspace layout (bytes); ws_size is 256 MB — we use ~9.3 MB
    char* ws = (char*)d_ws;
    float*  depth_ws = (float*) (ws + 0);          // 16 KB
    int*    rank_ws  = (int*)   (ws + 16384);      // 16 KB
    int*    inv_ws   = (int*)   (ws + 32768);      // 16 KB
    float4* A_uns    = (float4*)(ws + 49152);      // 64 KB
    float4* B_uns    = (float4*)(ws + 114688);     // 64 KB
    float*  C_uns    = (float*) (ws + 180224);     // 16 KB
    float4* D_uns    = (float4*)(ws + 196608);     // 64 KB
    unsigned long long* mask_ws = (unsigned long long*)(ws + 262144);  // 32 KB
    float4* E_A      = (float4*)(ws + 294912);     // 64*4096*16 = 4 MB
    float4* E_B      = (float4*)(ws + 4489216);    // 4 MB
    float*  E_C      = (float*) (ws + 8683520);    // 1 MB
    int*    tile_cnt = (int*)   (ws + 9732096);    // 256 B

    gs_prep<<<GS_N / 256, 256, 0, stream>>>(
        pws, low_shs, high_shs, alphas_raw, scales_raw, rots_raw, Rcw, tcw, cam,
        out_areas, depth_ws, rank_ws, A_uns, B_uns, C_uns, D_uns, mask_ws);

    gs_rank_partial<<<256, 256, 0, stream>>>(depth_ws, rank_ws);

    gs_gather_mask<<<GS_N / 256, 256, 0, stream>>>(
        rank_ws, D_uns, inv_ws, mask_ws);

    gs_expand<<<NTILES, 256, 0, stream>>>(
        mask_ws, inv_ws, A_uns, B_uns, C_uns, E_A, E_B, E_C, tile_cnt);

    gs_raster<<<NTILES * WAVES_PER_TILE, 256, 0, stream>>>(
        E_A, E_B, E_C, tile_cnt, out_img);
}